// Round 4
// baseline (350.408 us; speedup 1.0000x reference)
//
#include <hip/hip_runtime.h>
#include <stdint.h>

// AttentionLayer_27599459844127 — round 3:
//  * attn v4: in-block split-K. 4096 blocks (b,qt,h); 4 waves each own a 256-k
//    strip (4 tiles) -> 4x more blocks, 4x shorter serial chain; LDS merge of
//    partial (m,l,O) at block end. P-tile LDS aliased with merge buffer.
//  * kred fused into K-projection GEMM epilogue (pre-scaled by 0.125).
//  * 1/sqrt(DH) folded into Wq at transpose_cast time.
//  * launch consolidation: 1 cast kernel, 1 weight-transpose kernel, LDS-table scatter.

typedef __attribute__((ext_vector_type(8))) short short8;
typedef __attribute__((ext_vector_type(4))) float f32x4;
typedef __attribute__((ext_vector_type(4))) unsigned short ushort4v;
typedef __attribute__((ext_vector_type(2))) unsigned uint2v;
typedef __attribute__((ext_vector_type(4))) unsigned uint4v;

#define DEVI __device__ __forceinline__

constexpr float NEG_MIN = -3.4028234663852886e38f;
constexpr float LOG2E   = 1.4426950408889634f;

DEVI unsigned short f2b(float f) {
    union { float f; unsigned u; } x; x.f = f;
    unsigned u = x.u;
    unsigned r = (u + 0x7fffu + ((u >> 16) & 1u)) >> 16;  // RNE
    return (unsigned short)r;
}
DEVI float hi_as_f(unsigned p) { union { unsigned u; float f; } x; x.u = p & 0xffff0000u; return x.f; }
DEVI float lo_as_f(unsigned p) { union { unsigned u; float f; } x; x.u = p << 16; return x.f; }

// ---------------- cast f32 -> bf16: states then key_states in one launch ----------------
__global__ void __launch_bounds__(256) cast_inputs(const float* __restrict__ s0,
                                                   const float* __restrict__ s1,
                                                   unsigned short* __restrict__ d0,
                                                   unsigned short* __restrict__ d1) {
    int i = blockIdx.x * 256 + threadIdx.x;  // 2 * 1M float4 groups
    const float* src = (i < 1024 * 1024) ? s0 : s1;
    unsigned short* dst = (i < 1024 * 1024) ? d0 : d1;
    int j = i & (1024 * 1024 - 1);
    float4 v = reinterpret_cast<const float4*>(src)[j];
    ushort4v o;
    o.x = f2b(v.x); o.y = f2b(v.y); o.z = f2b(v.z); o.w = f2b(v.w);
    reinterpret_cast<ushort4v*>(dst)[j] = o;
}

// ---------------- transpose + cast all 4 weights (1024x1024 each), optional scale --------
__global__ void __launch_bounds__(256) transpose_weights(const float* __restrict__ Wq,
                                                         const float* __restrict__ Wk,
                                                         const float* __restrict__ Wv,
                                                         const float* __restrict__ Wo,
                                                         unsigned short* __restrict__ Wqt,
                                                         unsigned short* __restrict__ Wot) {
    __shared__ float t[64][65];
    int wi = blockIdx.x >> 8, sub = blockIdx.x & 255;
    const float* src = (wi == 0) ? Wq : ((wi == 1) ? Wk : ((wi == 2) ? Wv : Wo));
    unsigned short* dst = (wi == 3) ? Wot : (Wqt + (size_t)wi * 1024 * 1024);
    float scale = (wi == 0) ? 0.125f : 1.0f;
    const int R = 1024, C = 1024;
    int bc = sub & 15, br = sub >> 4;
    int tid = threadIdx.x;
    int r0 = tid >> 4, c4 = (tid & 15) << 2;
    for (int i = 0; i < 4; ++i) {
        int row = r0 + i * 16;
        float4 v = *reinterpret_cast<const float4*>(&src[(size_t)(br * 64 + row) * C + bc * 64 + c4]);
        t[row][c4] = v.x; t[row][c4 + 1] = v.y; t[row][c4 + 2] = v.z; t[row][c4 + 3] = v.w;
    }
    __syncthreads();
    int cr0 = tid >> 4, r4 = (tid & 15) << 2;
    for (int i = 0; i < 4; ++i) {
        int crow = cr0 + i * 16;
        ushort4v o;
        o.x = f2b(t[r4][crow] * scale); o.y = f2b(t[r4 + 1][crow] * scale);
        o.z = f2b(t[r4 + 2][crow] * scale); o.w = f2b(t[r4 + 3][crow] * scale);
        *reinterpret_cast<ushort4v*>(&dst[(size_t)(bc * 64 + crow) * R + br * 64 + r4]) = o;
    }
}

// ---------------- shared 128x128 GEMM tile body (optional kred epilogue) ----------------
template <int OUT_F32, int DO_KRED>
DEVI void gemm128_body(const unsigned short* __restrict__ A,
                       const unsigned short* __restrict__ Bt,
                       void* __restrict__ Cv, int bm, int bn,
                       unsigned short* As, unsigned short* Bs,
                       float* __restrict__ kredT) {
    const int Kd = 1024, N = 1024;
    int tid = threadIdx.x, l = tid & 63, w = tid >> 6;
    int wm = w >> 1, wn = w & 1;
    int l15 = l & 15, koff = (l >> 4) << 3;
    f32x4 acc[4][4] = {};
    const int arow = tid >> 2, acol = (tid & 3) << 3;
    const unsigned short* Ab = A + (size_t)(bm * 128) * Kd;
    const unsigned short* Bb = Bt + (size_t)(bn * 128) * Kd;
    for (int kt = 0; kt < Kd; kt += 32) {
        short8 va0 = *reinterpret_cast<const short8*>(&Ab[(size_t)arow * Kd + kt + acol]);
        short8 va1 = *reinterpret_cast<const short8*>(&Ab[(size_t)(arow + 64) * Kd + kt + acol]);
        short8 vb0 = *reinterpret_cast<const short8*>(&Bb[(size_t)arow * Kd + kt + acol]);
        short8 vb1 = *reinterpret_cast<const short8*>(&Bb[(size_t)(arow + 64) * Kd + kt + acol]);
        __syncthreads();
        *reinterpret_cast<short8*>(&As[arow * 40 + acol]) = va0;
        *reinterpret_cast<short8*>(&As[(arow + 64) * 40 + acol]) = va1;
        *reinterpret_cast<short8*>(&Bs[arow * 40 + acol]) = vb0;
        *reinterpret_cast<short8*>(&Bs[(arow + 64) * 40 + acol]) = vb1;
        __syncthreads();
        short8 af[4], bf[4];
        for (int m = 0; m < 4; ++m)
            af[m] = *reinterpret_cast<const short8*>(&As[(wm * 64 + m * 16 + l15) * 40 + koff]);
        for (int n = 0; n < 4; ++n)
            bf[n] = *reinterpret_cast<const short8*>(&Bs[(wn * 64 + n * 16 + l15) * 40 + koff]);
        for (int m = 0; m < 4; ++m)
            for (int n = 0; n < 4; ++n)
                acc[m][n] = __builtin_amdgcn_mfma_f32_16x16x32_bf16(af[m], bf[n], acc[m][n], 0, 0, 0);
    }
    for (int m = 0; m < 4; ++m)
        for (int n = 0; n < 4; ++n)
            for (int r = 0; r < 4; ++r) {
                int row = bm * 128 + wm * 64 + m * 16 + ((l >> 4) << 2) + r;
                int col = bn * 128 + wn * 64 + n * 16 + l15;
                float v = acc[m][n][r];
                if (OUT_F32) reinterpret_cast<float*>(Cv)[(size_t)row * N + col] = v;
                else reinterpret_cast<unsigned short*>(Cv)[(size_t)row * N + col] = f2b(v);
            }
    if (DO_KRED) {
        // this wave's 64 cols = exactly one head (h = bn*2+wn); row-sum -> kredT[b][h][s]*0.125
        int hw = bn * 2 + wn;
#pragma unroll
        for (int m = 0; m < 4; ++m) {
            f32x4 rs = (acc[m][0] + acc[m][1]) + (acc[m][2] + acc[m][3]);
#pragma unroll
            for (int d = 1; d < 16; d <<= 1) {
                f32x4 t;
                t[0] = __shfl_xor(rs[0], d); t[1] = __shfl_xor(rs[1], d);
                t[2] = __shfl_xor(rs[2], d); t[3] = __shfl_xor(rs[3], d);
                rs += t;
            }
            if (l15 == 0) {
#pragma unroll
                for (int r = 0; r < 4; ++r) {
                    int row = bm * 128 + wm * 64 + m * 16 + ((l >> 4) << 2) + r;
                    kredT[((size_t)((row >> 10) * 16 + hw) << 10) + (row & 1023)] = rs[r] * 0.125f;
                }
            }
        }
    }
}

__global__ void __launch_bounds__(256) gemm_qkv(const unsigned short* __restrict__ Sb,
                                                const unsigned short* __restrict__ Kb,
                                                const unsigned short* __restrict__ W3,
                                                unsigned short* __restrict__ Qb,
                                                unsigned short* __restrict__ Kbf,
                                                unsigned short* __restrict__ Vb,
                                                float* __restrict__ kredT) {
    __shared__ unsigned short As[128 * 40];
    __shared__ unsigned short Bs[128 * 40];
    int g = blockIdx.x >> 8, sub = blockIdx.x & 255;
    const unsigned short* A = (g == 0) ? Sb : Kb;
    const unsigned short* Bt = W3 + (size_t)g * (1024 * 1024);
    unsigned short* C = (g == 0) ? Qb : ((g == 1) ? Kbf : Vb);
    if (g == 1)
        gemm128_body<0, 1>(A, Bt, C, sub >> 3, sub & 7, As, Bs, kredT);
    else
        gemm128_body<0, 0>(A, Bt, C, sub >> 3, sub & 7, As, Bs, nullptr);
}

__global__ void __launch_bounds__(256) gemm_wo(const unsigned short* __restrict__ A,
                                               const unsigned short* __restrict__ Bt,
                                               float* __restrict__ C) {
    __shared__ unsigned short As[128 * 40];
    __shared__ unsigned short Bs[128 * 40];
    gemm128_body<1, 0>(A, Bt, C, blockIdx.x >> 3, blockIdx.x & 7, As, Bs, nullptr);
}

// ---------------- V [B,S,H,DH] -> Vt [B,H,DH,S] (bf16) ----------------
__global__ void __launch_bounds__(256) transpose_v(const unsigned short* __restrict__ V,
                                                   unsigned short* __restrict__ Vt) {
    __shared__ unsigned short t[64][66];
    int bid = blockIdx.x;
    int st = bid & 15, h = (bid >> 4) & 15, b = bid >> 8;
    int tid = threadIdx.x;
    int s = tid >> 2, c16 = (tid & 3) << 4;
    const unsigned short* src = V + ((size_t)((b * 1024 + st * 64 + s) * 16 + h)) * 64 + c16;
    short8 v0 = *reinterpret_cast<const short8*>(src);
    short8 v1 = *reinterpret_cast<const short8*>(src + 8);
    for (int j = 0; j < 8; ++j) {
        t[s][c16 + j] = (unsigned short)v0[j];
        t[s][c16 + 8 + j] = (unsigned short)v1[j];
    }
    __syncthreads();
    int a = tid >> 2, s16 = (tid & 3) << 4;
    short8 o0, o1;
    for (int j = 0; j < 8; ++j) {
        o0[j] = (short)t[s16 + j][a];
        o1[j] = (short)t[s16 + 8 + j][a];
    }
    unsigned short* dst = Vt + ((size_t)((b * 16 + h) * 64 + a)) * 1024 + st * 64 + s16;
    *reinterpret_cast<short8*>(dst) = o0;
    *reinterpret_cast<short8*>(dst + 8) = o1;
}

// ---------------- sparse bias scatter (transposed) with per-block LDS value table --------
__global__ void __launch_bounds__(256) scatter_bias(const int* __restrict__ ab,
                                                    const float* __restrict__ embs,
                                                    const float* __restrict__ scal,
                                                    float* __restrict__ bqkT, int n) {
    __shared__ float tab[64];
    int tid = threadIdx.x;
    if (tid < 64) {
        float v = 0.f;
        for (int a = 0; a < 64; ++a) v += embs[tid * 64 + a] * scal[a];
        tab[tid] = v;
    }
    __syncthreads();
    int i = blockIdx.x * 256 + tid;
    if (i >= n) return;
    int4 e = *reinterpret_cast<const int4*>(&ab[i * 4]);  // (b, q, k, eid)
    atomicAdd(&bqkT[((size_t)e.x * 1024 + e.z) * 1024 + e.y], tab[e.w]);
}

// ---------------- pack_T: pkT[b][k][q] = bf16(mask[b,q,k])<<16 | bf16(bqkT[b][k][q]) ------
__global__ void __launch_bounds__(256) pack_T(const float* __restrict__ masks,
                                              unsigned* __restrict__ pkT) {
    __shared__ float mt[64][65];
    int bid = blockIdx.x;
    int qt = bid & 15, ktile = (bid >> 4) & 15, b = bid >> 8;
    int tid = threadIdx.x;
    int row = tid >> 2, c16 = (tid & 3) << 4;
    const float* mrow = masks + ((size_t)(b * 1024 + qt * 64 + row)) * 1024 + ktile * 64 + c16;
    for (int j = 0; j < 16; j += 4) {
        float4 v = *reinterpret_cast<const float4*>(mrow + j);
        mt[row][c16 + j] = v.x; mt[row][c16 + j + 1] = v.y;
        mt[row][c16 + j + 2] = v.z; mt[row][c16 + j + 3] = v.w;
    }
    __syncthreads();
    unsigned* orow = pkT + ((size_t)(b * 1024 + ktile * 64 + row)) * 1024 + qt * 64 + c16;
    for (int j = 0; j < 16; j += 4) {
        float4 bv = *reinterpret_cast<const float4*>(reinterpret_cast<float*>(orow + j));
        uint4v o;
        o.x = ((unsigned)f2b(mt[c16 + j][row]) << 16)     | f2b(bv.x);
        o.y = ((unsigned)f2b(mt[c16 + j + 1][row]) << 16) | f2b(bv.y);
        o.z = ((unsigned)f2b(mt[c16 + j + 2][row]) << 16) | f2b(bv.z);
        o.w = ((unsigned)f2b(mt[c16 + j + 3][row]) << 16) | f2b(bv.w);
        *reinterpret_cast<uint4v*>(orow + j) = o;
    }
}

// ---------------- fused attention v4: in-block split-K + LDS merge ----------------
// grid = B * qt(64) * H(16) = 4096; block = 4 waves; wave w -> k strip [w*256, w*256+256).
__global__ void __launch_bounds__(256, 6) attn_kernel(const unsigned short* __restrict__ Q,
                                                      const unsigned short* __restrict__ K,
                                                      const unsigned short* __restrict__ Vt,
                                                      const unsigned* __restrict__ pkT,
                                                      const float* __restrict__ kredT,
                                                      unsigned short* __restrict__ ctx) {
    // p_s (9216B) aliased inside the 17408B merge buffer; barrier separates uses.
    __shared__ __align__(16) char smem[4 * 16 * 68 * 4];
    auto p_s = reinterpret_cast<unsigned short(*)[16][72]>(smem);  // [4][16][72]
    auto Om  = reinterpret_cast<float(*)[16][68]>(smem);           // [4][16][68]
    __shared__ float Mm[4][16], Lm[4][16];

    int bid = blockIdx.x;
    int h = bid & 15, qt = (bid >> 4) & 63, b = bid >> 10;
    int tid = threadIdx.x, w = tid >> 6, l = tid & 63;
    int qbase = qt * 16;
    int l15 = l & 15, l16 = l >> 4;
    int koff = l16 << 3;
    int k0 = w << 8;

    short8 qf0, qf1;
    {
        const unsigned short* qp = Q + ((size_t)((b * 1024 + qbase + l15) * 16 + h)) * 64 + koff;
        qf0 = *reinterpret_cast<const short8*>(qp);
        qf1 = *reinterpret_cast<const short8*>(qp + 32);
    }
    const unsigned* pkp = pkT + ((size_t)b << 20) + qbase + l15;       // + k*1024
    const float* krp = kredT + ((size_t)(b * 16 + h) << 10);           // + k (pre-scaled .125)
    const unsigned short* Kp = K + ((size_t)b << 20) + h * 64 + koff;  // + s*1024
    const unsigned short* Vp = Vt + ((size_t)(b * 16 + h) << 16);      // + d*1024 + s

    float m_r = -INFINITY, l_r = 0.f;
    f32x4 O[4] = {};
    short8 kf[8];
    unsigned pkv[16];

#pragma unroll
    for (int n = 0; n < 4; ++n) {
        const unsigned short* kp = Kp + ((size_t)(k0 + n * 16 + l15) << 10);
        kf[n * 2] = *reinterpret_cast<const short8*>(kp);
        kf[n * 2 + 1] = *reinterpret_cast<const short8*>(kp + 32);
#pragma unroll
        for (int r = 0; r < 4; ++r)
            pkv[n * 4 + r] = pkp[(size_t)(k0 + n * 16 + l16 * 4 + r) << 10];
    }

    for (int it = 0; it < 4; ++it) {
        int kbase = k0 + it * 64;

        short8 vf[8];
#pragma unroll
        for (int ks = 0; ks < 2; ++ks)
#pragma unroll
            for (int af = 0; af < 4; ++af)
                vf[ks * 4 + af] = *reinterpret_cast<const short8*>(
                    Vp + ((size_t)(af * 16 + l15) << 10) + kbase + ks * 32 + koff);

        // QK^T swapped: C[row=k][col=q]; Q pre-scaled by 0.125
        f32x4 sacc[4] = {};
#pragma unroll
        for (int n = 0; n < 4; ++n) {
            sacc[n] = __builtin_amdgcn_mfma_f32_16x16x32_bf16(kf[n * 2], qf0, sacc[n], 0, 0, 0);
            sacc[n] = __builtin_amdgcn_mfma_f32_16x16x32_bf16(kf[n * 2 + 1], qf1, sacc[n], 0, 0, 0);
        }
        if (it < 3) {
#pragma unroll
            for (int n = 0; n < 4; ++n) {
                const unsigned short* kp = Kp + ((size_t)(kbase + 64 + n * 16 + l15) << 10);
                kf[n * 2] = *reinterpret_cast<const short8*>(kp);
                kf[n * 2 + 1] = *reinterpret_cast<const short8*>(kp + 32);
            }
        }

        float lg[16], tmax = -INFINITY;
#pragma unroll
        for (int n = 0; n < 4; ++n)
#pragma unroll
            for (int r = 0; r < 4; ++r) {
                int i = n * 4 + r;
                float mv = hi_as_f(pkv[i]);
                float bq = lo_as_f(pkv[i]);
                float krv = krp[kbase + n * 16 + l16 * 4 + r];  // pre-scaled 0.125
                float sv = fmaf(bq, krv, sacc[n][r]);
                float v = sv * mv;
                if (!(mv > 0.f)) v += NEG_MIN;
                lg[i] = v;
                tmax = fmaxf(tmax, v);
            }
        float mvs[16];
#pragma unroll
        for (int i = 0; i < 16; ++i) mvs[i] = hi_as_f(pkv[i]);
        if (it < 3) {
#pragma unroll
            for (int n = 0; n < 4; ++n)
#pragma unroll
                for (int r = 0; r < 4; ++r)
                    pkv[n * 4 + r] = pkp[(size_t)(kbase + 64 + n * 16 + l16 * 4 + r) << 10];
        }

        tmax = fmaxf(tmax, __shfl_xor(tmax, 16));
        tmax = fmaxf(tmax, __shfl_xor(tmax, 32));
        float nm = fmaxf(m_r, tmax);
        float al = exp2f((m_r - nm) * LOG2E);
        m_r = nm;

        float ps = 0.f;
#pragma unroll
        for (int n = 0; n < 4; ++n) {
            float p0 = exp2f((lg[n * 4 + 0] - m_r) * LOG2E);
            float p1 = exp2f((lg[n * 4 + 1] - m_r) * LOG2E);
            float p2 = exp2f((lg[n * 4 + 2] - m_r) * LOG2E);
            float p3 = exp2f((lg[n * 4 + 3] - m_r) * LOG2E);
            ps += (p0 + p1) + (p2 + p3);
            uint2v pk2;
            pk2.x = (unsigned)f2b(p0 * mvs[n * 4 + 0]) | ((unsigned)f2b(p1 * mvs[n * 4 + 1]) << 16);
            pk2.y = (unsigned)f2b(p2 * mvs[n * 4 + 2]) | ((unsigned)f2b(p3 * mvs[n * 4 + 3]) << 16);
            *reinterpret_cast<uint2v*>(&p_s[w][l15][n * 16 + (l16 << 2)]) = pk2;
        }
        ps += __shfl_xor(ps, 16);
        ps += __shfl_xor(ps, 32);
        l_r = l_r * al + ps;

        float alr[4];
#pragma unroll
        for (int r = 0; r < 4; ++r) alr[r] = __shfl(al, l16 * 4 + r);
#pragma unroll
        for (int af = 0; af < 4; ++af)
#pragma unroll
            for (int r = 0; r < 4; ++r) O[af][r] *= alr[r];

#pragma unroll
        for (int ks = 0; ks < 2; ++ks) {
            short8 pa = *reinterpret_cast<const short8*>(&p_s[w][l15][ks * 32 + koff]);
#pragma unroll
            for (int af = 0; af < 4; ++af)
                O[af] = __builtin_amdgcn_mfma_f32_16x16x32_bf16(pa, vf[ks * 4 + af], O[af], 0, 0, 0);
        }
    }

    __syncthreads();  // all waves done with p_s before aliasing as Om
#pragma unroll
    for (int af = 0; af < 4; ++af)
#pragma unroll
        for (int r = 0; r < 4; ++r)
            Om[w][l16 * 4 + r][af * 16 + l15] = O[af][r];
    if (l16 == 0) { Mm[w][l15] = m_r; Lm[w][l15] = l_r; }
    __syncthreads();

    // merge 4 partials: thread -> (q = tid>>4, 4 d's)
    int q = tid >> 4, dd = (tid & 15) << 2;
    float M = fmaxf(fmaxf(Mm[0][q], Mm[1][q]), fmaxf(Mm[2][q], Mm[3][q]));
    float L = 0.f, a0 = 0.f, a1 = 0.f, a2 = 0.f, a3 = 0.f;
#pragma unroll
    for (int ww = 0; ww < 4; ++ww) {
        float mw = Mm[ww][q];
        float e = (mw == -INFINITY) ? 0.f : exp2f((mw - M) * LOG2E);
        L += e * Lm[ww][q];
        const float* op = &Om[ww][q][dd];
        a0 = fmaf(e, op[0], a0); a1 = fmaf(e, op[1], a1);
        a2 = fmaf(e, op[2], a2); a3 = fmaf(e, op[3], a3);
    }
    float inv = (L > 0.f) ? 1.f / L : 0.f;
    ushort4v o;
    o.x = f2b(a0 * inv); o.y = f2b(a1 * inv); o.z = f2b(a2 * inv); o.w = f2b(a3 * inv);
    *reinterpret_cast<ushort4v*>(&ctx[((size_t)((b * 1024 + qbase + q) * 16 + h)) * 64 + dd]) = o;
}

// ---------------- host launch ----------------
extern "C" void kernel_launch(void* const* d_in, const int* in_sizes, int n_in,
                              void* d_out, int out_size, void* d_ws, size_t ws_size,
                              hipStream_t stream) {
    const float* states     = (const float*)d_in[0];
    const float* key_states = (const float*)d_in[1];
    const float* masks      = (const float*)d_in[2];
    const int*   ab         = (const int*)d_in[3];
    const float* Wq         = (const float*)d_in[4];
    const float* Wk         = (const float*)d_in[5];
    const float* Wv         = (const float*)d_in[6];
    const float* Wo         = (const float*)d_in[7];
    const float* embs       = (const float*)d_in[8];
    const float* scal       = (const float*)d_in[9];

    char* ws = (char*)d_ws;
    const size_t MB = 1024 * 1024;
    unsigned short* Sb   = (unsigned short*)(ws);
    unsigned short* Kb   = (unsigned short*)(ws + 8 * MB);
    float*          bqkT = (float*)(ws);                     // overlays Sb/Kb after QKV GEMM
    unsigned short* Wqt  = (unsigned short*)(ws + 16 * MB);  // Wq^T,Wk^T,Wv^T (6MB)
    unsigned short* Wot  = (unsigned short*)(ws + 22 * MB);
    unsigned short* Qb   = (unsigned short*)(ws + 24 * MB);
    unsigned short* Kbf  = (unsigned short*)(ws + 32 * MB);
    unsigned short* Vb   = (unsigned short*)(ws + 40 * MB);  // dead after transpose_v
    unsigned short* ctx  = (unsigned short*)(ws + 40 * MB);  // reuses Vb region
    unsigned short* Vt   = (unsigned short*)(ws + 48 * MB);
    float*          krdT = (float*)(ws + 56 * MB);           // 256KB
    (void)in_sizes; (void)n_in; (void)out_size; (void)ws_size;

    cast_inputs<<<8192, 256, 0, stream>>>(states, key_states, Sb, Kb);
    transpose_weights<<<1024, 256, 0, stream>>>(Wq, Wk, Wv, Wo, Wqt, Wot);

    gemm_qkv<<<768, 256, 0, stream>>>(Sb, Kb, Wqt, Qb, Kbf, Vb, krdT);
    transpose_v<<<1024, 256, 0, stream>>>(Vb, Vt);

    // bqkT overlays Sb/Kb — safe only after gemm_qkv consumed them (stream order).
    hipMemsetAsync(bqkT, 0, (size_t)4 * 1024 * 1024 * 4, stream);
    scatter_bias<<<64, 256, 0, stream>>>(ab, embs, scal, bqkT, 16384);
    pack_T<<<1024, 256, 0, stream>>>(masks, (unsigned*)bqkT);

    attn_kernel<<<4096, 256, 0, stream>>>(Qb, Kbf, Vt, (const unsigned*)bqkT, krdT, ctx);

    gemm_wo<<<256, 256, 0, stream>>>(ctx, Wot, (float*)d_out);
}

// Round 5
// 300.081 us; speedup vs baseline: 1.1677x; 1.1677x over previous
//
#include <hip/hip_runtime.h>
#include <stdint.h>

// AttentionLayer_27599459844127 — round 4:
//  * attn v5: grid 1024 (b,qt,hgroup) — restores v3's pkT/K/V L2 reuse (R3's
//    per-head grid caused 416MB HBM traffic) — but 512-thread blocks:
//    8 waves = 4 heads x 2 k-strips (8 tiles each). LDS merge of the 2 partials
//    per head. kred via 1 coalesced load + shfl distribute. No reg prefetch
//    (registers -> occupancy; TLP hides latency).

typedef __attribute__((ext_vector_type(8))) short short8;
typedef __attribute__((ext_vector_type(4))) float f32x4;
typedef __attribute__((ext_vector_type(4))) unsigned short ushort4v;
typedef __attribute__((ext_vector_type(2))) unsigned uint2v;
typedef __attribute__((ext_vector_type(4))) unsigned uint4v;

#define DEVI __device__ __forceinline__

constexpr float NEG_MIN = -3.4028234663852886e38f;
constexpr float LOG2E   = 1.4426950408889634f;

DEVI unsigned short f2b(float f) {
    union { float f; unsigned u; } x; x.f = f;
    unsigned u = x.u;
    unsigned r = (u + 0x7fffu + ((u >> 16) & 1u)) >> 16;  // RNE
    return (unsigned short)r;
}
DEVI float hi_as_f(unsigned p) { union { unsigned u; float f; } x; x.u = p & 0xffff0000u; return x.f; }
DEVI float lo_as_f(unsigned p) { union { unsigned u; float f; } x; x.u = p << 16; return x.f; }

// ---------------- cast f32 -> bf16: states then key_states in one launch ----------------
__global__ void __launch_bounds__(256) cast_inputs(const float* __restrict__ s0,
                                                   const float* __restrict__ s1,
                                                   unsigned short* __restrict__ d0,
                                                   unsigned short* __restrict__ d1) {
    int i = blockIdx.x * 256 + threadIdx.x;  // 2 * 1M float4 groups
    const float* src = (i < 1024 * 1024) ? s0 : s1;
    unsigned short* dst = (i < 1024 * 1024) ? d0 : d1;
    int j = i & (1024 * 1024 - 1);
    float4 v = reinterpret_cast<const float4*>(src)[j];
    ushort4v o;
    o.x = f2b(v.x); o.y = f2b(v.y); o.z = f2b(v.z); o.w = f2b(v.w);
    reinterpret_cast<ushort4v*>(dst)[j] = o;
}

// ---------------- transpose + cast all 4 weights (1024x1024 each), optional scale --------
__global__ void __launch_bounds__(256) transpose_weights(const float* __restrict__ Wq,
                                                         const float* __restrict__ Wk,
                                                         const float* __restrict__ Wv,
                                                         const float* __restrict__ Wo,
                                                         unsigned short* __restrict__ Wqt,
                                                         unsigned short* __restrict__ Wot) {
    __shared__ float t[64][65];
    int wi = blockIdx.x >> 8, sub = blockIdx.x & 255;
    const float* src = (wi == 0) ? Wq : ((wi == 1) ? Wk : ((wi == 2) ? Wv : Wo));
    unsigned short* dst = (wi == 3) ? Wot : (Wqt + (size_t)wi * 1024 * 1024);
    float scale = (wi == 0) ? 0.125f : 1.0f;
    const int R = 1024, C = 1024;
    int bc = sub & 15, br = sub >> 4;
    int tid = threadIdx.x;
    int r0 = tid >> 4, c4 = (tid & 15) << 2;
    for (int i = 0; i < 4; ++i) {
        int row = r0 + i * 16;
        float4 v = *reinterpret_cast<const float4*>(&src[(size_t)(br * 64 + row) * C + bc * 64 + c4]);
        t[row][c4] = v.x; t[row][c4 + 1] = v.y; t[row][c4 + 2] = v.z; t[row][c4 + 3] = v.w;
    }
    __syncthreads();
    int cr0 = tid >> 4, r4 = (tid & 15) << 2;
    for (int i = 0; i < 4; ++i) {
        int crow = cr0 + i * 16;
        ushort4v o;
        o.x = f2b(t[r4][crow] * scale); o.y = f2b(t[r4 + 1][crow] * scale);
        o.z = f2b(t[r4 + 2][crow] * scale); o.w = f2b(t[r4 + 3][crow] * scale);
        *reinterpret_cast<ushort4v*>(&dst[(size_t)(bc * 64 + crow) * R + br * 64 + r4]) = o;
    }
}

// ---------------- shared 128x128 GEMM tile body (optional kred epilogue) ----------------
template <int OUT_F32, int DO_KRED>
DEVI void gemm128_body(const unsigned short* __restrict__ A,
                       const unsigned short* __restrict__ Bt,
                       void* __restrict__ Cv, int bm, int bn,
                       unsigned short* As, unsigned short* Bs,
                       float* __restrict__ kredT) {
    const int Kd = 1024, N = 1024;
    int tid = threadIdx.x, l = tid & 63, w = tid >> 6;
    int wm = w >> 1, wn = w & 1;
    int l15 = l & 15, koff = (l >> 4) << 3;
    f32x4 acc[4][4] = {};
    const int arow = tid >> 2, acol = (tid & 3) << 3;
    const unsigned short* Ab = A + (size_t)(bm * 128) * Kd;
    const unsigned short* Bb = Bt + (size_t)(bn * 128) * Kd;
    for (int kt = 0; kt < Kd; kt += 32) {
        short8 va0 = *reinterpret_cast<const short8*>(&Ab[(size_t)arow * Kd + kt + acol]);
        short8 va1 = *reinterpret_cast<const short8*>(&Ab[(size_t)(arow + 64) * Kd + kt + acol]);
        short8 vb0 = *reinterpret_cast<const short8*>(&Bb[(size_t)arow * Kd + kt + acol]);
        short8 vb1 = *reinterpret_cast<const short8*>(&Bb[(size_t)(arow + 64) * Kd + kt + acol]);
        __syncthreads();
        *reinterpret_cast<short8*>(&As[arow * 40 + acol]) = va0;
        *reinterpret_cast<short8*>(&As[(arow + 64) * 40 + acol]) = va1;
        *reinterpret_cast<short8*>(&Bs[arow * 40 + acol]) = vb0;
        *reinterpret_cast<short8*>(&Bs[(arow + 64) * 40 + acol]) = vb1;
        __syncthreads();
        short8 af[4], bf[4];
        for (int m = 0; m < 4; ++m)
            af[m] = *reinterpret_cast<const short8*>(&As[(wm * 64 + m * 16 + l15) * 40 + koff]);
        for (int n = 0; n < 4; ++n)
            bf[n] = *reinterpret_cast<const short8*>(&Bs[(wn * 64 + n * 16 + l15) * 40 + koff]);
        for (int m = 0; m < 4; ++m)
            for (int n = 0; n < 4; ++n)
                acc[m][n] = __builtin_amdgcn_mfma_f32_16x16x32_bf16(af[m], bf[n], acc[m][n], 0, 0, 0);
    }
    for (int m = 0; m < 4; ++m)
        for (int n = 0; n < 4; ++n)
            for (int r = 0; r < 4; ++r) {
                int row = bm * 128 + wm * 64 + m * 16 + ((l >> 4) << 2) + r;
                int col = bn * 128 + wn * 64 + n * 16 + l15;
                float v = acc[m][n][r];
                if (OUT_F32) reinterpret_cast<float*>(Cv)[(size_t)row * N + col] = v;
                else reinterpret_cast<unsigned short*>(Cv)[(size_t)row * N + col] = f2b(v);
            }
    if (DO_KRED) {
        // this wave's 64 cols = exactly one head (h = bn*2+wn); row-sum -> kredT[b][h][s]*0.125
        int hw = bn * 2 + wn;
#pragma unroll
        for (int m = 0; m < 4; ++m) {
            f32x4 rs = (acc[m][0] + acc[m][1]) + (acc[m][2] + acc[m][3]);
#pragma unroll
            for (int d = 1; d < 16; d <<= 1) {
                f32x4 t;
                t[0] = __shfl_xor(rs[0], d); t[1] = __shfl_xor(rs[1], d);
                t[2] = __shfl_xor(rs[2], d); t[3] = __shfl_xor(rs[3], d);
                rs += t;
            }
            if (l15 == 0) {
#pragma unroll
                for (int r = 0; r < 4; ++r) {
                    int row = bm * 128 + wm * 64 + m * 16 + ((l >> 4) << 2) + r;
                    kredT[((size_t)((row >> 10) * 16 + hw) << 10) + (row & 1023)] = rs[r] * 0.125f;
                }
            }
        }
    }
}

__global__ void __launch_bounds__(256) gemm_qkv(const unsigned short* __restrict__ Sb,
                                                const unsigned short* __restrict__ Kb,
                                                const unsigned short* __restrict__ W3,
                                                unsigned short* __restrict__ Qb,
                                                unsigned short* __restrict__ Kbf,
                                                unsigned short* __restrict__ Vb,
                                                float* __restrict__ kredT) {
    __shared__ unsigned short As[128 * 40];
    __shared__ unsigned short Bs[128 * 40];
    int g = blockIdx.x >> 8, sub = blockIdx.x & 255;
    const unsigned short* A = (g == 0) ? Sb : Kb;
    const unsigned short* Bt = W3 + (size_t)g * (1024 * 1024);
    unsigned short* C = (g == 0) ? Qb : ((g == 1) ? Kbf : Vb);
    if (g == 1)
        gemm128_body<0, 1>(A, Bt, C, sub >> 3, sub & 7, As, Bs, kredT);
    else
        gemm128_body<0, 0>(A, Bt, C, sub >> 3, sub & 7, As, Bs, nullptr);
}

__global__ void __launch_bounds__(256) gemm_wo(const unsigned short* __restrict__ A,
                                               const unsigned short* __restrict__ Bt,
                                               float* __restrict__ C) {
    __shared__ unsigned short As[128 * 40];
    __shared__ unsigned short Bs[128 * 40];
    gemm128_body<1, 0>(A, Bt, C, blockIdx.x >> 3, blockIdx.x & 7, As, Bs, nullptr);
}

// ---------------- V [B,S,H,DH] -> Vt [B,H,DH,S] (bf16) ----------------
__global__ void __launch_bounds__(256) transpose_v(const unsigned short* __restrict__ V,
                                                   unsigned short* __restrict__ Vt) {
    __shared__ unsigned short t[64][66];
    int bid = blockIdx.x;
    int st = bid & 15, h = (bid >> 4) & 15, b = bid >> 8;
    int tid = threadIdx.x;
    int s = tid >> 2, c16 = (tid & 3) << 4;
    const unsigned short* src = V + ((size_t)((b * 1024 + st * 64 + s) * 16 + h)) * 64 + c16;
    short8 v0 = *reinterpret_cast<const short8*>(src);
    short8 v1 = *reinterpret_cast<const short8*>(src + 8);
    for (int j = 0; j < 8; ++j) {
        t[s][c16 + j] = (unsigned short)v0[j];
        t[s][c16 + 8 + j] = (unsigned short)v1[j];
    }
    __syncthreads();
    int a = tid >> 2, s16 = (tid & 3) << 4;
    short8 o0, o1;
    for (int j = 0; j < 8; ++j) {
        o0[j] = (short)t[s16 + j][a];
        o1[j] = (short)t[s16 + 8 + j][a];
    }
    unsigned short* dst = Vt + ((size_t)((b * 16 + h) * 64 + a)) * 1024 + st * 64 + s16;
    *reinterpret_cast<short8*>(dst) = o0;
    *reinterpret_cast<short8*>(dst + 8) = o1;
}

// ---------------- sparse bias scatter (transposed) with per-block LDS value table --------
__global__ void __launch_bounds__(256) scatter_bias(const int* __restrict__ ab,
                                                    const float* __restrict__ embs,
                                                    const float* __restrict__ scal,
                                                    float* __restrict__ bqkT, int n) {
    __shared__ float tab[64];
    int tid = threadIdx.x;
    if (tid < 64) {
        float v = 0.f;
        for (int a = 0; a < 64; ++a) v += embs[tid * 64 + a] * scal[a];
        tab[tid] = v;
    }
    __syncthreads();
    int i = blockIdx.x * 256 + tid;
    if (i >= n) return;
    int4 e = *reinterpret_cast<const int4*>(&ab[i * 4]);  // (b, q, k, eid)
    atomicAdd(&bqkT[((size_t)e.x * 1024 + e.z) * 1024 + e.y], tab[e.w]);
}

// ---------------- pack_T: pkT[b][k][q] = bf16(mask[b,q,k])<<16 | bf16(bqkT[b][k][q]) ------
__global__ void __launch_bounds__(256) pack_T(const float* __restrict__ masks,
                                              unsigned* __restrict__ pkT) {
    __shared__ float mt[64][65];
    int bid = blockIdx.x;
    int qt = bid & 15, ktile = (bid >> 4) & 15, b = bid >> 8;
    int tid = threadIdx.x;
    int row = tid >> 2, c16 = (tid & 3) << 4;
    const float* mrow = masks + ((size_t)(b * 1024 + qt * 64 + row)) * 1024 + ktile * 64 + c16;
    for (int j = 0; j < 16; j += 4) {
        float4 v = *reinterpret_cast<const float4*>(mrow + j);
        mt[row][c16 + j] = v.x; mt[row][c16 + j + 1] = v.y;
        mt[row][c16 + j + 2] = v.z; mt[row][c16 + j + 3] = v.w;
    }
    __syncthreads();
    unsigned* orow = pkT + ((size_t)(b * 1024 + ktile * 64 + row)) * 1024 + qt * 64 + c16;
    for (int j = 0; j < 16; j += 4) {
        float4 bv = *reinterpret_cast<const float4*>(reinterpret_cast<float*>(orow + j));
        uint4v o;
        o.x = ((unsigned)f2b(mt[c16 + j][row]) << 16)     | f2b(bv.x);
        o.y = ((unsigned)f2b(mt[c16 + j + 1][row]) << 16) | f2b(bv.y);
        o.z = ((unsigned)f2b(mt[c16 + j + 2][row]) << 16) | f2b(bv.z);
        o.w = ((unsigned)f2b(mt[c16 + j + 3][row]) << 16) | f2b(bv.w);
        *reinterpret_cast<uint4v*>(orow + j) = o;
    }
}

// ---------------- fused attention v5: 8 waves = 4 heads x 2 k-strips + LDS merge ---------
// grid = B * qt(64) * hg(4) = 1024; block = 512 thr. wave w: head hg*4+(w&3),
// k-strip (w>>2) -> 8 tiles of 64.
__global__ void __launch_bounds__(512, 6) attn_kernel(const unsigned short* __restrict__ Q,
                                                      const unsigned short* __restrict__ K,
                                                      const unsigned short* __restrict__ Vt,
                                                      const unsigned* __restrict__ pkT,
                                                      const float* __restrict__ kredT,
                                                      unsigned short* __restrict__ ctx) {
    // p_s [8][16][72] ushort (18432B) aliased by Om [4][16][68] f32 (17408B).
    __shared__ __align__(16) char smem[8 * 16 * 72 * 2];
    auto p_s = reinterpret_cast<unsigned short(*)[16][72]>(smem);
    auto Om  = reinterpret_cast<float(*)[16][68]>(smem);
    __shared__ float Mm[4][16], Lm[4][16];

    int bid = blockIdx.x;
    int hg = bid & 3, qt = (bid >> 2) & 63, b = bid >> 8;
    int tid = threadIdx.x, w = tid >> 6, l = tid & 63;
    int h = hg * 4 + (w & 3);
    int k0 = (w >> 2) << 9;  // strip base: 0 or 512
    int qbase = qt * 16;
    int l15 = l & 15, l16 = l >> 4;
    int koff = l16 << 3;

    short8 qf0, qf1;
    {
        const unsigned short* qp = Q + ((size_t)((b * 1024 + qbase + l15) * 16 + h)) * 64 + koff;
        qf0 = *reinterpret_cast<const short8*>(qp);
        qf1 = *reinterpret_cast<const short8*>(qp + 32);
    }
    const unsigned* pkp = pkT + ((size_t)b << 20) + qbase + l15;       // + k*1024
    const float* krp = kredT + ((size_t)(b * 16 + h) << 10);           // + k (pre-scaled .125)
    const unsigned short* Kp = K + ((size_t)b << 20) + h * 64 + koff;  // + s*1024
    const unsigned short* Vp = Vt + ((size_t)(b * 16 + h) << 16);      // + d*1024 + s

    float m_r = -INFINITY, l_r = 0.f;  // per-lane, q = qbase + l15
    f32x4 O[4] = {};

    for (int it = 0; it < 8; ++it) {
        int kbase = k0 + it * 64;

        // kred: one coalesced 256B load, distribute via shfl
        float kr_l = krp[kbase + l];

        // K frags + pk gathers (independent; issue all)
        short8 kf[8];
#pragma unroll
        for (int n = 0; n < 4; ++n) {
            const unsigned short* kp = Kp + ((size_t)(kbase + n * 16 + l15) << 10);
            kf[n * 2] = *reinterpret_cast<const short8*>(kp);
            kf[n * 2 + 1] = *reinterpret_cast<const short8*>(kp + 32);
        }
        unsigned pkv[16];
#pragma unroll
        for (int n = 0; n < 4; ++n)
#pragma unroll
            for (int r = 0; r < 4; ++r)
                pkv[n * 4 + r] = pkp[(size_t)(kbase + n * 16 + l16 * 4 + r) << 10];

        // QK^T swapped: C[row=k][col=q]; Q pre-scaled by 0.125
        f32x4 sacc[4] = {};
#pragma unroll
        for (int n = 0; n < 4; ++n) {
            sacc[n] = __builtin_amdgcn_mfma_f32_16x16x32_bf16(kf[n * 2], qf0, sacc[n], 0, 0, 0);
            sacc[n] = __builtin_amdgcn_mfma_f32_16x16x32_bf16(kf[n * 2 + 1], qf1, sacc[n], 0, 0, 0);
        }

        // V loads issued early (used at tile end)
        short8 vf[8];
#pragma unroll
        for (int ks = 0; ks < 2; ++ks)
#pragma unroll
            for (int af = 0; af < 4; ++af)
                vf[ks * 4 + af] = *reinterpret_cast<const short8*>(
                    Vp + ((size_t)(af * 16 + l15) << 10) + kbase + ks * 32 + koff);

        // logits in place (sacc <- masked logit); kred pre-scaled by 0.125
        float tmax = -INFINITY;
#pragma unroll
        for (int n = 0; n < 4; ++n)
#pragma unroll
            for (int r = 0; r < 4; ++r) {
                unsigned pv = pkv[n * 4 + r];
                float mv = hi_as_f(pv);
                float bq = lo_as_f(pv);
                float krv = __shfl(kr_l, n * 16 + l16 * 4 + r);
                float v = fmaf(bq, krv, sacc[n][r]) * mv;
                if (!(mv > 0.f)) v += NEG_MIN;
                sacc[n][r] = v;
                tmax = fmaxf(tmax, v);
            }
        tmax = fmaxf(tmax, __shfl_xor(tmax, 16));
        tmax = fmaxf(tmax, __shfl_xor(tmax, 32));
        float nm = fmaxf(m_r, tmax);
        float al = exp2f((m_r - nm) * LOG2E);
        m_r = nm;

        float ps = 0.f;
#pragma unroll
        for (int n = 0; n < 4; ++n) {
            float p0 = exp2f((sacc[n][0] - m_r) * LOG2E);
            float p1 = exp2f((sacc[n][1] - m_r) * LOG2E);
            float p2 = exp2f((sacc[n][2] - m_r) * LOG2E);
            float p3 = exp2f((sacc[n][3] - m_r) * LOG2E);
            ps += (p0 + p1) + (p2 + p3);
            uint2v pk2;
            pk2.x = (unsigned)f2b(p0 * hi_as_f(pkv[n * 4 + 0])) |
                    ((unsigned)f2b(p1 * hi_as_f(pkv[n * 4 + 1])) << 16);
            pk2.y = (unsigned)f2b(p2 * hi_as_f(pkv[n * 4 + 2])) |
                    ((unsigned)f2b(p3 * hi_as_f(pkv[n * 4 + 3])) << 16);
            *reinterpret_cast<uint2v*>(&p_s[w][l15][n * 16 + (l16 << 2)]) = pk2;
        }
        ps += __shfl_xor(ps, 16);
        ps += __shfl_xor(ps, 32);
        l_r = l_r * al + ps;

        float alr[4];
#pragma unroll
        for (int r = 0; r < 4; ++r) alr[r] = __shfl(al, l16 * 4 + r);
#pragma unroll
        for (int af = 0; af < 4; ++af)
#pragma unroll
            for (int r = 0; r < 4; ++r) O[af][r] *= alr[r];

        // PV: A = per-wave P tile (same-wave LDS), B = V rows
#pragma unroll
        for (int ks = 0; ks < 2; ++ks) {
            short8 pa = *reinterpret_cast<const short8*>(&p_s[w][l15][ks * 32 + koff]);
#pragma unroll
            for (int af = 0; af < 4; ++af)
                O[af] = __builtin_amdgcn_mfma_f32_16x16x32_bf16(pa, vf[ks * 4 + af], O[af], 0, 0, 0);
        }
    }

    // -------- merge the two k-strips per head --------
    __syncthreads();  // everyone done with p_s before aliasing as Om
    if (w >= 4) {
#pragma unroll
        for (int af = 0; af < 4; ++af)
#pragma unroll
            for (int r = 0; r < 4; ++r)
                Om[w - 4][l16 * 4 + r][af * 16 + l15] = O[af][r];
        if (l16 == 0) { Mm[w - 4][l15] = m_r; Lm[w - 4][l15] = l_r; }
    }
    __syncthreads();
    if (w < 4) {
        float m_row[4], l_row[4];
#pragma unroll
        for (int r = 0; r < 4; ++r) {
            m_row[r] = __shfl(m_r, l16 * 4 + r);
            l_row[r] = __shfl(l_r, l16 * 4 + r);
        }
#pragma unroll
        for (int r = 0; r < 4; ++r) {
            int row = l16 * 4 + r;
            float mp = Mm[w][row], lp = Lm[w][row];
            float M = fmaxf(m_row[r], mp);
            float e0 = (m_row[r] == -INFINITY) ? 0.f : exp2f((m_row[r] - M) * LOG2E);
            float e1 = (mp == -INFINITY) ? 0.f : exp2f((mp - M) * LOG2E);
            float L = e0 * l_row[r] + e1 * lp;
            float inv = (L > 0.f) ? 1.f / L : 0.f;
#pragma unroll
            for (int af = 0; af < 4; ++af) {
                float v = (e0 * O[af][r] + e1 * Om[w][row][af * 16 + l15]) * inv;
                ctx[((size_t)((b * 1024 + qbase + row) * 16 + h)) * 64 + af * 16 + l15] = f2b(v);
            }
        }
    }
}

// ---------------- host launch ----------------
extern "C" void kernel_launch(void* const* d_in, const int* in_sizes, int n_in,
                              void* d_out, int out_size, void* d_ws, size_t ws_size,
                              hipStream_t stream) {
    const float* states     = (const float*)d_in[0];
    const float* key_states = (const float*)d_in[1];
    const float* masks      = (const float*)d_in[2];
    const int*   ab         = (const int*)d_in[3];
    const float* Wq         = (const float*)d_in[4];
    const float* Wk         = (const float*)d_in[5];
    const float* Wv         = (const float*)d_in[6];
    const float* Wo         = (const float*)d_in[7];
    const float* embs       = (const float*)d_in[8];
    const float* scal       = (const float*)d_in[9];

    char* ws = (char*)d_ws;
    const size_t MB = 1024 * 1024;
    unsigned short* Sb   = (unsigned short*)(ws);
    unsigned short* Kb   = (unsigned short*)(ws + 8 * MB);
    float*          bqkT = (float*)(ws);                     // overlays Sb/Kb after QKV GEMM
    unsigned short* Wqt  = (unsigned short*)(ws + 16 * MB);  // Wq^T,Wk^T,Wv^T (6MB)
    unsigned short* Wot  = (unsigned short*)(ws + 22 * MB);
    unsigned short* Qb   = (unsigned short*)(ws + 24 * MB);
    unsigned short* Kbf  = (unsigned short*)(ws + 32 * MB);
    unsigned short* Vb   = (unsigned short*)(ws + 40 * MB);  // dead after transpose_v
    unsigned short* ctx  = (unsigned short*)(ws + 40 * MB);  // reuses Vb region
    unsigned short* Vt   = (unsigned short*)(ws + 48 * MB);
    float*          krdT = (float*)(ws + 56 * MB);           // 256KB
    (void)in_sizes; (void)n_in; (void)out_size; (void)ws_size;

    cast_inputs<<<8192, 256, 0, stream>>>(states, key_states, Sb, Kb);
    transpose_weights<<<1024, 256, 0, stream>>>(Wq, Wk, Wv, Wo, Wqt, Wot);

    gemm_qkv<<<768, 256, 0, stream>>>(Sb, Kb, Wqt, Qb, Kbf, Vb, krdT);
    transpose_v<<<1024, 256, 0, stream>>>(Vb, Vt);

    // bqkT overlays Sb/Kb — safe only after gemm_qkv consumed them (stream order).
    hipMemsetAsync(bqkT, 0, (size_t)4 * 1024 * 1024 * 4, stream);
    scatter_bias<<<64, 256, 0, stream>>>(ab, embs, scal, bqkT, 16384);
    pack_T<<<1024, 256, 0, stream>>>(masks, (unsigned*)bqkT);

    attn_kernel<<<1024, 512, 0, stream>>>(Qb, Kbf, Vt, (const unsigned*)bqkT, krdT, ctx);

    gemm_wo<<<256, 256, 0, stream>>>(ctx, Wot, (float*)d_out);
}

// Round 6
// 186.997 us; speedup vs baseline: 1.8739x; 1.6047x over previous
//
#include <hip/hip_runtime.h>
#include <stdint.h>

// AttentionLayer_27599459844127 — round 5:
//  * attn v6: same-head blocks (1 head x 64 q-rows, 4 waves x 16q), K/V tiles
//    cooperatively staged in LDS (coalesced, 4x fewer L2 lines), pk gathers
//    direct + register-rotated, 2 barriers/tile (m97 pattern), XCD swizzle so
//    each (b,h)'s 16 q-blocks share one XCD L2. launch_bounds(256,4) — no
//    forced spills (R3/R4 lesson: VGPR_Count=40 => scratch => FETCH blowup).

typedef __attribute__((ext_vector_type(8))) short short8;
typedef __attribute__((ext_vector_type(4))) float f32x4;
typedef __attribute__((ext_vector_type(4))) unsigned short ushort4v;
typedef __attribute__((ext_vector_type(2))) unsigned uint2v;
typedef __attribute__((ext_vector_type(4))) unsigned uint4v;

#define DEVI __device__ __forceinline__

constexpr float NEG_MIN = -3.4028234663852886e38f;
constexpr float LOG2E   = 1.4426950408889634f;

DEVI unsigned short f2b(float f) {
    union { float f; unsigned u; } x; x.f = f;
    unsigned u = x.u;
    unsigned r = (u + 0x7fffu + ((u >> 16) & 1u)) >> 16;  // RNE
    return (unsigned short)r;
}
DEVI float hi_as_f(unsigned p) { union { unsigned u; float f; } x; x.u = p & 0xffff0000u; return x.f; }
DEVI float lo_as_f(unsigned p) { union { unsigned u; float f; } x; x.u = p << 16; return x.f; }

// ---------------- cast f32 -> bf16: states then key_states in one launch ----------------
__global__ void __launch_bounds__(256) cast_inputs(const float* __restrict__ s0,
                                                   const float* __restrict__ s1,
                                                   unsigned short* __restrict__ d0,
                                                   unsigned short* __restrict__ d1) {
    int i = blockIdx.x * 256 + threadIdx.x;  // 2 * 1M float4 groups
    const float* src = (i < 1024 * 1024) ? s0 : s1;
    unsigned short* dst = (i < 1024 * 1024) ? d0 : d1;
    int j = i & (1024 * 1024 - 1);
    float4 v = reinterpret_cast<const float4*>(src)[j];
    ushort4v o;
    o.x = f2b(v.x); o.y = f2b(v.y); o.z = f2b(v.z); o.w = f2b(v.w);
    reinterpret_cast<ushort4v*>(dst)[j] = o;
}

// ---------------- transpose + cast all 4 weights (1024x1024 each), optional scale --------
__global__ void __launch_bounds__(256) transpose_weights(const float* __restrict__ Wq,
                                                         const float* __restrict__ Wk,
                                                         const float* __restrict__ Wv,
                                                         const float* __restrict__ Wo,
                                                         unsigned short* __restrict__ Wqt,
                                                         unsigned short* __restrict__ Wot) {
    __shared__ float t[64][65];
    int wi = blockIdx.x >> 8, sub = blockIdx.x & 255;
    const float* src = (wi == 0) ? Wq : ((wi == 1) ? Wk : ((wi == 2) ? Wv : Wo));
    unsigned short* dst = (wi == 3) ? Wot : (Wqt + (size_t)wi * 1024 * 1024);
    float scale = (wi == 0) ? 0.125f : 1.0f;
    const int R = 1024, C = 1024;
    int bc = sub & 15, br = sub >> 4;
    int tid = threadIdx.x;
    int r0 = tid >> 4, c4 = (tid & 15) << 2;
    for (int i = 0; i < 4; ++i) {
        int row = r0 + i * 16;
        float4 v = *reinterpret_cast<const float4*>(&src[(size_t)(br * 64 + row) * C + bc * 64 + c4]);
        t[row][c4] = v.x; t[row][c4 + 1] = v.y; t[row][c4 + 2] = v.z; t[row][c4 + 3] = v.w;
    }
    __syncthreads();
    int cr0 = tid >> 4, r4 = (tid & 15) << 2;
    for (int i = 0; i < 4; ++i) {
        int crow = cr0 + i * 16;
        ushort4v o;
        o.x = f2b(t[r4][crow] * scale); o.y = f2b(t[r4 + 1][crow] * scale);
        o.z = f2b(t[r4 + 2][crow] * scale); o.w = f2b(t[r4 + 3][crow] * scale);
        *reinterpret_cast<ushort4v*>(&dst[(size_t)(bc * 64 + crow) * R + br * 64 + r4]) = o;
    }
}

// ---------------- shared 128x128 GEMM tile body (optional kred epilogue) ----------------
template <int OUT_F32, int DO_KRED>
DEVI void gemm128_body(const unsigned short* __restrict__ A,
                       const unsigned short* __restrict__ Bt,
                       void* __restrict__ Cv, int bm, int bn,
                       unsigned short* As, unsigned short* Bs,
                       float* __restrict__ kredT) {
    const int Kd = 1024, N = 1024;
    int tid = threadIdx.x, l = tid & 63, w = tid >> 6;
    int wm = w >> 1, wn = w & 1;
    int l15 = l & 15, koff = (l >> 4) << 3;
    f32x4 acc[4][4] = {};
    const int arow = tid >> 2, acol = (tid & 3) << 3;
    const unsigned short* Ab = A + (size_t)(bm * 128) * Kd;
    const unsigned short* Bb = Bt + (size_t)(bn * 128) * Kd;
    for (int kt = 0; kt < Kd; kt += 32) {
        short8 va0 = *reinterpret_cast<const short8*>(&Ab[(size_t)arow * Kd + kt + acol]);
        short8 va1 = *reinterpret_cast<const short8*>(&Ab[(size_t)(arow + 64) * Kd + kt + acol]);
        short8 vb0 = *reinterpret_cast<const short8*>(&Bb[(size_t)arow * Kd + kt + acol]);
        short8 vb1 = *reinterpret_cast<const short8*>(&Bb[(size_t)(arow + 64) * Kd + kt + acol]);
        __syncthreads();
        *reinterpret_cast<short8*>(&As[arow * 40 + acol]) = va0;
        *reinterpret_cast<short8*>(&As[(arow + 64) * 40 + acol]) = va1;
        *reinterpret_cast<short8*>(&Bs[arow * 40 + acol]) = vb0;
        *reinterpret_cast<short8*>(&Bs[(arow + 64) * 40 + acol]) = vb1;
        __syncthreads();
        short8 af[4], bf[4];
        for (int m = 0; m < 4; ++m)
            af[m] = *reinterpret_cast<const short8*>(&As[(wm * 64 + m * 16 + l15) * 40 + koff]);
        for (int n = 0; n < 4; ++n)
            bf[n] = *reinterpret_cast<const short8*>(&Bs[(wn * 64 + n * 16 + l15) * 40 + koff]);
        for (int m = 0; m < 4; ++m)
            for (int n = 0; n < 4; ++n)
                acc[m][n] = __builtin_amdgcn_mfma_f32_16x16x32_bf16(af[m], bf[n], acc[m][n], 0, 0, 0);
    }
    for (int m = 0; m < 4; ++m)
        for (int n = 0; n < 4; ++n)
            for (int r = 0; r < 4; ++r) {
                int row = bm * 128 + wm * 64 + m * 16 + ((l >> 4) << 2) + r;
                int col = bn * 128 + wn * 64 + n * 16 + l15;
                float v = acc[m][n][r];
                if (OUT_F32) reinterpret_cast<float*>(Cv)[(size_t)row * N + col] = v;
                else reinterpret_cast<unsigned short*>(Cv)[(size_t)row * N + col] = f2b(v);
            }
    if (DO_KRED) {
        // this wave's 64 cols = exactly one head (h = bn*2+wn); row-sum -> kredT[b][h][s]*0.125
        int hw = bn * 2 + wn;
#pragma unroll
        for (int m = 0; m < 4; ++m) {
            f32x4 rs = (acc[m][0] + acc[m][1]) + (acc[m][2] + acc[m][3]);
#pragma unroll
            for (int d = 1; d < 16; d <<= 1) {
                f32x4 t;
                t[0] = __shfl_xor(rs[0], d); t[1] = __shfl_xor(rs[1], d);
                t[2] = __shfl_xor(rs[2], d); t[3] = __shfl_xor(rs[3], d);
                rs += t;
            }
            if (l15 == 0) {
#pragma unroll
                for (int r = 0; r < 4; ++r) {
                    int row = bm * 128 + wm * 64 + m * 16 + ((l >> 4) << 2) + r;
                    kredT[((size_t)((row >> 10) * 16 + hw) << 10) + (row & 1023)] = rs[r] * 0.125f;
                }
            }
        }
    }
}

__global__ void __launch_bounds__(256) gemm_qkv(const unsigned short* __restrict__ Sb,
                                                const unsigned short* __restrict__ Kb,
                                                const unsigned short* __restrict__ W3,
                                                unsigned short* __restrict__ Qb,
                                                unsigned short* __restrict__ Kbf,
                                                unsigned short* __restrict__ Vb,
                                                float* __restrict__ kredT) {
    __shared__ unsigned short As[128 * 40];
    __shared__ unsigned short Bs[128 * 40];
    int g = blockIdx.x >> 8, sub = blockIdx.x & 255;
    const unsigned short* A = (g == 0) ? Sb : Kb;
    const unsigned short* Bt = W3 + (size_t)g * (1024 * 1024);
    unsigned short* C = (g == 0) ? Qb : ((g == 1) ? Kbf : Vb);
    if (g == 1)
        gemm128_body<0, 1>(A, Bt, C, sub >> 3, sub & 7, As, Bs, kredT);
    else
        gemm128_body<0, 0>(A, Bt, C, sub >> 3, sub & 7, As, Bs, nullptr);
}

__global__ void __launch_bounds__(256) gemm_wo(const unsigned short* __restrict__ A,
                                               const unsigned short* __restrict__ Bt,
                                               float* __restrict__ C) {
    __shared__ unsigned short As[128 * 40];
    __shared__ unsigned short Bs[128 * 40];
    gemm128_body<1, 0>(A, Bt, C, blockIdx.x >> 3, blockIdx.x & 7, As, Bs, nullptr);
}

// ---------------- V [B,S,H,DH] -> Vt [B,H,DH,S] (bf16) ----------------
__global__ void __launch_bounds__(256) transpose_v(const unsigned short* __restrict__ V,
                                                   unsigned short* __restrict__ Vt) {
    __shared__ unsigned short t[64][66];
    int bid = blockIdx.x;
    int st = bid & 15, h = (bid >> 4) & 15, b = bid >> 8;
    int tid = threadIdx.x;
    int s = tid >> 2, c16 = (tid & 3) << 4;
    const unsigned short* src = V + ((size_t)((b * 1024 + st * 64 + s) * 16 + h)) * 64 + c16;
    short8 v0 = *reinterpret_cast<const short8*>(src);
    short8 v1 = *reinterpret_cast<const short8*>(src + 8);
    for (int j = 0; j < 8; ++j) {
        t[s][c16 + j] = (unsigned short)v0[j];
        t[s][c16 + 8 + j] = (unsigned short)v1[j];
    }
    __syncthreads();
    int a = tid >> 2, s16 = (tid & 3) << 4;
    short8 o0, o1;
    for (int j = 0; j < 8; ++j) {
        o0[j] = (short)t[s16 + j][a];
        o1[j] = (short)t[s16 + 8 + j][a];
    }
    unsigned short* dst = Vt + ((size_t)((b * 16 + h) * 64 + a)) * 1024 + st * 64 + s16;
    *reinterpret_cast<short8*>(dst) = o0;
    *reinterpret_cast<short8*>(dst + 8) = o1;
}

// ---------------- sparse bias scatter (transposed) with per-block LDS value table --------
__global__ void __launch_bounds__(256) scatter_bias(const int* __restrict__ ab,
                                                    const float* __restrict__ embs,
                                                    const float* __restrict__ scal,
                                                    float* __restrict__ bqkT, int n) {
    __shared__ float tab[64];
    int tid = threadIdx.x;
    if (tid < 64) {
        float v = 0.f;
        for (int a = 0; a < 64; ++a) v += embs[tid * 64 + a] * scal[a];
        tab[tid] = v;
    }
    __syncthreads();
    int i = blockIdx.x * 256 + tid;
    if (i >= n) return;
    int4 e = *reinterpret_cast<const int4*>(&ab[i * 4]);  // (b, q, k, eid)
    atomicAdd(&bqkT[((size_t)e.x * 1024 + e.z) * 1024 + e.y], tab[e.w]);
}

// ---------------- pack_T: pkT[b][k][q] = bf16(mask[b,q,k])<<16 | bf16(bqkT[b][k][q]) ------
__global__ void __launch_bounds__(256) pack_T(const float* __restrict__ masks,
                                              unsigned* __restrict__ pkT) {
    __shared__ float mt[64][65];
    int bid = blockIdx.x;
    int qt = bid & 15, ktile = (bid >> 4) & 15, b = bid >> 8;
    int tid = threadIdx.x;
    int row = tid >> 2, c16 = (tid & 3) << 4;
    const float* mrow = masks + ((size_t)(b * 1024 + qt * 64 + row)) * 1024 + ktile * 64 + c16;
    for (int j = 0; j < 16; j += 4) {
        float4 v = *reinterpret_cast<const float4*>(mrow + j);
        mt[row][c16 + j] = v.x; mt[row][c16 + j + 1] = v.y;
        mt[row][c16 + j + 2] = v.z; mt[row][c16 + j + 3] = v.w;
    }
    __syncthreads();
    unsigned* orow = pkT + ((size_t)(b * 1024 + ktile * 64 + row)) * 1024 + qt * 64 + c16;
    for (int j = 0; j < 16; j += 4) {
        float4 bv = *reinterpret_cast<const float4*>(reinterpret_cast<float*>(orow + j));
        uint4v o;
        o.x = ((unsigned)f2b(mt[c16 + j][row]) << 16)     | f2b(bv.x);
        o.y = ((unsigned)f2b(mt[c16 + j + 1][row]) << 16) | f2b(bv.y);
        o.z = ((unsigned)f2b(mt[c16 + j + 2][row]) << 16) | f2b(bv.z);
        o.w = ((unsigned)f2b(mt[c16 + j + 3][row]) << 16) | f2b(bv.w);
        *reinterpret_cast<uint4v*>(orow + j) = o;
    }
}

// ---------------- fused attention v6: same-head block, LDS-staged K/V ----------------
// grid = 1024: g = bid%64 -> (b,h), qb = bid/64 -> q range [qb*64, +64).
// 4 waves x 16 q-rows, all same head -> K/V staged once per block per tile.
__global__ void __launch_bounds__(256, 4) attn_kernel(const unsigned short* __restrict__ Q,
                                                      const unsigned short* __restrict__ K,
                                                      const unsigned short* __restrict__ Vt,
                                                      const unsigned* __restrict__ pkT,
                                                      const float* __restrict__ kredT,
                                                      unsigned short* __restrict__ ctx) {
    __shared__ __align__(16) unsigned short Ks[64][72];  // [k][d], pad 72 -> 2-way max
    __shared__ __align__(16) unsigned short Vs[64][72];  // [d][k]
    __shared__ __align__(16) unsigned short p_s[4][16][72];

    int bid = blockIdx.x;
    int g = bid & 63, qb = bid >> 6;   // all 16 qb-blocks of g land on XCD g%8
    int b = g >> 4, h = g & 15;
    int tid = threadIdx.x, w = tid >> 6, l = tid & 63;
    int qbase = qb * 64 + w * 16;
    int l15 = l & 15, l16 = l >> 4, koff = l16 << 3;

    // staging indices: 256 threads cover 32 rows x 64 cols (16B each), 2 passes
    int srow = tid >> 3, scol = (tid & 7) << 3;

    const unsigned short* Kg = K + ((size_t)b << 20) + h * 64 + scol;                    // + s*1024
    const unsigned short* Vg = Vt + ((size_t)(b * 16 + h) << 16) + (size_t)srow * 1024 + scol;  // + k
    const unsigned* pkp = pkT + ((size_t)b << 20) + qbase + l15;                         // + k*1024
    const float* krp = kredT + ((size_t)(b * 16 + h) << 10);                             // + k
    const unsigned short* Vpr = Vt + ((size_t)(b * 16 + h) << 16);                       // epilogue unused

    short8 qf0, qf1;
    {
        const unsigned short* qp = Q + ((size_t)((b * 1024 + qbase + l15) * 16 + h)) * 64 + koff;
        qf0 = *reinterpret_cast<const short8*>(qp);
        qf1 = *reinterpret_cast<const short8*>(qp + 32);
    }

    // prefetch tile 0 staging regs + gathers
    short8 kpre0 = *reinterpret_cast<const short8*>(Kg + (size_t)srow * 1024);
    short8 kpre1 = *reinterpret_cast<const short8*>(Kg + (size_t)(srow + 32) * 1024);
    short8 vpre0 = *reinterpret_cast<const short8*>(Vg);
    short8 vpre1 = *reinterpret_cast<const short8*>(Vg + (size_t)32 * 1024);
    unsigned pkv[16];
#pragma unroll
    for (int n = 0; n < 4; ++n)
#pragma unroll
        for (int r = 0; r < 4; ++r)
            pkv[n * 4 + r] = pkp[(size_t)(n * 16 + l16 * 4 + r) << 10];
    float kr_l = krp[l];

    float m_r = -INFINITY, l_r = 0.f;  // per-lane, q = qbase + l15
    f32x4 O[4] = {};

    for (int kt = 0; kt < 16; ++kt) {
        int kbase = kt * 64;

        __syncthreads();  // all waves done reading Ks/Vs of previous tile
        *reinterpret_cast<short8*>(&Ks[srow][scol]) = kpre0;
        *reinterpret_cast<short8*>(&Ks[srow + 32][scol]) = kpre1;
        *reinterpret_cast<short8*>(&Vs[srow][scol]) = vpre0;
        *reinterpret_cast<short8*>(&Vs[srow + 32][scol]) = vpre1;
        __syncthreads();  // staged tile visible

        // prefetch next tile's staging regs (latency covered by compute below)
        if (kt < 15) {
            int nb = kbase + 64;
            kpre0 = *reinterpret_cast<const short8*>(Kg + (size_t)(nb + srow) * 1024);
            kpre1 = *reinterpret_cast<const short8*>(Kg + (size_t)(nb + srow + 32) * 1024);
            vpre0 = *reinterpret_cast<const short8*>(Vg + nb);
            vpre1 = *reinterpret_cast<const short8*>(Vg + (size_t)32 * 1024 + nb);
        }

        // QK^T swapped: C[row=k][col=q]; Q pre-scaled by 0.125
        f32x4 sacc[4] = {};
#pragma unroll
        for (int n = 0; n < 4; ++n) {
            short8 kf0 = *reinterpret_cast<const short8*>(&Ks[n * 16 + l15][koff]);
            short8 kf1 = *reinterpret_cast<const short8*>(&Ks[n * 16 + l15][32 + koff]);
            sacc[n] = __builtin_amdgcn_mfma_f32_16x16x32_bf16(kf0, qf0, sacc[n], 0, 0, 0);
            sacc[n] = __builtin_amdgcn_mfma_f32_16x16x32_bf16(kf1, qf1, sacc[n], 0, 0, 0);
        }

        // logits in place; kred distributed by shfl (pre-scaled 0.125)
        float tmax = -INFINITY;
#pragma unroll
        for (int n = 0; n < 4; ++n)
#pragma unroll
            for (int r = 0; r < 4; ++r) {
                unsigned pv = pkv[n * 4 + r];
                float mv = hi_as_f(pv);
                float bq = lo_as_f(pv);
                float krv = __shfl(kr_l, n * 16 + l16 * 4 + r);
                float v = fmaf(bq, krv, sacc[n][r]) * mv;
                if (!(mv > 0.f)) v += NEG_MIN;
                sacc[n][r] = v;
                tmax = fmaxf(tmax, v);
            }
        tmax = fmaxf(tmax, __shfl_xor(tmax, 16));
        tmax = fmaxf(tmax, __shfl_xor(tmax, 32));
        float nm = fmaxf(m_r, tmax);
        float al = exp2f((m_r - nm) * LOG2E);
        m_r = nm;

        float ps = 0.f;
#pragma unroll
        for (int n = 0; n < 4; ++n) {
            float p0 = exp2f((sacc[n][0] - m_r) * LOG2E);
            float p1 = exp2f((sacc[n][1] - m_r) * LOG2E);
            float p2 = exp2f((sacc[n][2] - m_r) * LOG2E);
            float p3 = exp2f((sacc[n][3] - m_r) * LOG2E);
            ps += (p0 + p1) + (p2 + p3);
            uint2v pk2;
            pk2.x = (unsigned)f2b(p0 * hi_as_f(pkv[n * 4 + 0])) |
                    ((unsigned)f2b(p1 * hi_as_f(pkv[n * 4 + 1])) << 16);
            pk2.y = (unsigned)f2b(p2 * hi_as_f(pkv[n * 4 + 2])) |
                    ((unsigned)f2b(p3 * hi_as_f(pkv[n * 4 + 3])) << 16);
            *reinterpret_cast<uint2v*>(&p_s[w][l15][n * 16 + (l16 << 2)]) = pk2;
        }

        // pkv/kred consumed -> rotate in next tile's gathers (in flight across PV)
        if (kt < 15) {
#pragma unroll
            for (int n = 0; n < 4; ++n)
#pragma unroll
                for (int r = 0; r < 4; ++r)
                    pkv[n * 4 + r] = pkp[(size_t)(kbase + 64 + n * 16 + l16 * 4 + r) << 10];
            kr_l = krp[kbase + 64 + l];
        }

        ps += __shfl_xor(ps, 16);
        ps += __shfl_xor(ps, 32);
        l_r = l_r * al + ps;

        float alr[4];
#pragma unroll
        for (int r = 0; r < 4; ++r) alr[r] = __shfl(al, l16 * 4 + r);
#pragma unroll
        for (int af = 0; af < 4; ++af)
#pragma unroll
            for (int r = 0; r < 4; ++r) O[af][r] *= alr[r];

        // PV: A = per-wave P tile (LDS), B = staged V rows
#pragma unroll
        for (int ks = 0; ks < 2; ++ks) {
            short8 pa = *reinterpret_cast<const short8*>(&p_s[w][l15][ks * 32 + koff]);
#pragma unroll
            for (int af = 0; af < 4; ++af) {
                short8 vb = *reinterpret_cast<const short8*>(&Vs[af * 16 + l15][ks * 32 + koff]);
                O[af] = __builtin_amdgcn_mfma_f32_16x16x32_bf16(pa, vb, O[af], 0, 0, 0);
            }
        }
    }
    (void)Vpr;

    float llr[4];
#pragma unroll
    for (int r = 0; r < 4; ++r) llr[r] = __shfl(l_r, l16 * 4 + r);
#pragma unroll
    for (int af = 0; af < 4; ++af)
#pragma unroll
        for (int r = 0; r < 4; ++r) {
            int row = l16 * 4 + r;
            float v = O[af][r] / llr[r];
            ctx[((size_t)((b * 1024 + qbase + row) * 16 + h)) * 64 + af * 16 + l15] = f2b(v);
        }
}

// ---------------- host launch ----------------
extern "C" void kernel_launch(void* const* d_in, const int* in_sizes, int n_in,
                              void* d_out, int out_size, void* d_ws, size_t ws_size,
                              hipStream_t stream) {
    const float* states     = (const float*)d_in[0];
    const float* key_states = (const float*)d_in[1];
    const float* masks      = (const float*)d_in[2];
    const int*   ab         = (const int*)d_in[3];
    const float* Wq         = (const float*)d_in[4];
    const float* Wk         = (const float*)d_in[5];
    const float* Wv         = (const float*)d_in[6];
    const float* Wo         = (const float*)d_in[7];
    const float* embs       = (const float*)d_in[8];
    const float* scal       = (const float*)d_in[9];

    char* ws = (char*)d_ws;
    const size_t MB = 1024 * 1024;
    unsigned short* Sb   = (unsigned short*)(ws);
    unsigned short* Kb   = (unsigned short*)(ws + 8 * MB);
    float*          bqkT = (float*)(ws);                     // overlays Sb/Kb after QKV GEMM
    unsigned short* Wqt  = (unsigned short*)(ws + 16 * MB);  // Wq^T,Wk^T,Wv^T (6MB)
    unsigned short* Wot  = (unsigned short*)(ws + 22 * MB);
    unsigned short* Qb   = (unsigned short*)(ws + 24 * MB);
    unsigned short* Kbf  = (unsigned short*)(ws + 32 * MB);
    unsigned short* Vb   = (unsigned short*)(ws + 40 * MB);  // dead after transpose_v
    unsigned short* ctx  = (unsigned short*)(ws + 40 * MB);  // reuses Vb region
    unsigned short* Vt   = (unsigned short*)(ws + 48 * MB);
    float*          krdT = (float*)(ws + 56 * MB);           // 256KB
    (void)in_sizes; (void)n_in; (void)out_size; (void)ws_size;

    cast_inputs<<<8192, 256, 0, stream>>>(states, key_states, Sb, Kb);
    transpose_weights<<<1024, 256, 0, stream>>>(Wq, Wk, Wv, Wo, Wqt, Wot);

    gemm_qkv<<<768, 256, 0, stream>>>(Sb, Kb, Wqt, Qb, Kbf, Vb, krdT);
    transpose_v<<<1024, 256, 0, stream>>>(Vb, Vt);

    // bqkT overlays Sb/Kb — safe only after gemm_qkv consumed them (stream order).
    hipMemsetAsync(bqkT, 0, (size_t)4 * 1024 * 1024 * 4, stream);
    scatter_bias<<<64, 256, 0, stream>>>(ab, embs, scal, bqkT, 16384);
    pack_T<<<1024, 256, 0, stream>>>(masks, (unsigned*)bqkT);

    attn_kernel<<<1024, 256, 0, stream>>>(Qb, Kbf, Vt, (const unsigned*)bqkT, krdT, ctx);

    gemm_wo<<<256, 256, 0, stream>>>(ctx, Wot, (float*)d_out);
}

// Round 7
// 159.724 us; speedup vs baseline: 2.1938x; 1.1707x over previous
//
#include <hip/hip_runtime.h>
#include <stdint.h>

// AttentionLayer_27599459844127 — round 6:
//  * GEMMs upgraded to m97 structure: global_load_lds width-16 into linear
//    [128][32] LDS, 2 barriers per K-step.
//  * attn v7: Ks/Vs linear [64][64] + XOR swizzle (write-side 8-way conflict in
//    v6's padded layout), kred via broadcast float4 (kills 16 ds_bpermute/tile),
//    v_cvt_pk_bf16_f32 P-pack, defer-max (THR=5 nat-log units).
//  * launch fusion: prep (cast+Wt), zero+transpose_v. 9 -> 7 launches.

typedef __attribute__((ext_vector_type(8))) short short8;
typedef __attribute__((ext_vector_type(4))) float f32x4;
typedef __attribute__((ext_vector_type(4))) unsigned short ushort4v;
typedef __attribute__((ext_vector_type(2))) unsigned uint2v;
typedef __attribute__((ext_vector_type(4))) unsigned uint4v;

#define DEVI __device__ __forceinline__

constexpr float NEG_MIN = -3.4028234663852886e38f;
constexpr float LOG2E   = 1.4426950408889634f;

DEVI unsigned short f2b(float f) {
    union { float f; unsigned u; } x; x.f = f;
    unsigned u = x.u;
    unsigned r = (u + 0x7fffu + ((u >> 16) & 1u)) >> 16;  // RNE
    return (unsigned short)r;
}
DEVI float hi_as_f(unsigned p) { union { unsigned u; float f; } x; x.u = p & 0xffff0000u; return x.f; }
DEVI float lo_as_f(unsigned p) { union { unsigned u; float f; } x; x.u = p << 16; return x.f; }

DEVI void gl_lds16(const unsigned short* g, unsigned short* l) {
    __builtin_amdgcn_global_load_lds(
        (const __attribute__((address_space(1))) unsigned int*)g,
        (__attribute__((address_space(3))) unsigned int*)l, 16, 0, 0);
}

// swizzled K/V LDS access: row*128B + (slot^(row&7))*16B
DEVI short8 ldkv(const unsigned short* base, int row, int slot) {
    return *reinterpret_cast<const short8*>(
        reinterpret_cast<const char*>(base) + row * 128 + (((slot ^ (row & 7)) & 7) << 4));
}

// ---------------- prep: cast inputs (blocks 0..8191) + weight transpose (8192..9215) -----
__global__ void __launch_bounds__(256) prep_kernel(const float* __restrict__ s0,
                                                   const float* __restrict__ s1,
                                                   const float* __restrict__ Wq,
                                                   const float* __restrict__ Wk,
                                                   const float* __restrict__ Wv,
                                                   const float* __restrict__ Wo,
                                                   unsigned short* __restrict__ d0,
                                                   unsigned short* __restrict__ d1,
                                                   unsigned short* __restrict__ Wqt,
                                                   unsigned short* __restrict__ Wot) {
    __shared__ float t[64][65];
    int bid = blockIdx.x, tid = threadIdx.x;
    if (bid < 8192) {
        int i = bid * 256 + tid;
        const float* src = (i < 1024 * 1024) ? s0 : s1;
        unsigned short* dst = (i < 1024 * 1024) ? d0 : d1;
        int j = i & (1024 * 1024 - 1);
        float4 v = reinterpret_cast<const float4*>(src)[j];
        ushort4v o;
        o.x = f2b(v.x); o.y = f2b(v.y); o.z = f2b(v.z); o.w = f2b(v.w);
        reinterpret_cast<ushort4v*>(dst)[j] = o;
        return;
    }
    int wb = bid - 8192;
    int wi = wb >> 8, sub = wb & 255;
    const float* src = (wi == 0) ? Wq : ((wi == 1) ? Wk : ((wi == 2) ? Wv : Wo));
    unsigned short* dst = (wi == 3) ? Wot : (Wqt + (size_t)wi * 1024 * 1024);
    float scale = (wi == 0) ? 0.125f : 1.0f;
    const int R = 1024, C = 1024;
    int bc = sub & 15, br = sub >> 4;
    int r0 = tid >> 4, c4 = (tid & 15) << 2;
    for (int i = 0; i < 4; ++i) {
        int row = r0 + i * 16;
        float4 v = *reinterpret_cast<const float4*>(&src[(size_t)(br * 64 + row) * C + bc * 64 + c4]);
        t[row][c4] = v.x; t[row][c4 + 1] = v.y; t[row][c4 + 2] = v.z; t[row][c4 + 3] = v.w;
    }
    __syncthreads();
    int cr0 = tid >> 4, r4 = (tid & 15) << 2;
    for (int i = 0; i < 4; ++i) {
        int crow = cr0 + i * 16;
        ushort4v o;
        o.x = f2b(t[r4][crow] * scale); o.y = f2b(t[r4 + 1][crow] * scale);
        o.z = f2b(t[r4 + 2][crow] * scale); o.w = f2b(t[r4 + 3][crow] * scale);
        *reinterpret_cast<ushort4v*>(&dst[(size_t)(bc * 64 + crow) * R + br * 64 + r4]) = o;
    }
}

// ---------------- GEMM 128x128 tile, global_load_lds staging (m97 structure) ------------
template <int OUT_F32, int DO_KRED>
DEVI void gemm128_body(const unsigned short* __restrict__ A,
                       const unsigned short* __restrict__ Bt,
                       void* __restrict__ Cv, int bm, int bn,
                       unsigned short* As, unsigned short* Bs,
                       float* __restrict__ kredT) {
    const int Kd = 1024, N = 1024;
    int tid = threadIdx.x, l = tid & 63, w = tid >> 6;
    int wm = w >> 1, wn = w & 1;
    int l15 = l & 15, koff = (l >> 4) << 3;
    f32x4 acc[4][4] = {};
    // staging: wave w owns rows [w*32, w*32+32) of each tile; 2 instrs of 16 rows.
    int srow = l >> 2, scol = (l & 3) << 3;
    const unsigned short* Ag = A + (size_t)(bm * 128 + w * 32 + srow) * Kd + scol;
    const unsigned short* Bg = Bt + (size_t)(bn * 128 + w * 32 + srow) * Kd + scol;
    unsigned short* AsW = As + w * 1024;  // linear [128][32], row = 64B
    unsigned short* BsW = Bs + w * 1024;
    for (int kt = 0; kt < Kd; kt += 32) {
        __syncthreads();  // all waves done reading previous tile
        gl_lds16(Ag + kt, AsW);
        gl_lds16(Ag + kt + (size_t)16 * Kd, AsW + 512);
        gl_lds16(Bg + kt, BsW);
        gl_lds16(Bg + kt + (size_t)16 * Kd, BsW + 512);
        __syncthreads();  // vmcnt drained -> staged tile visible
        short8 af[4], bf[4];
#pragma unroll
        for (int m = 0; m < 4; ++m)
            af[m] = *reinterpret_cast<const short8*>(&As[(wm * 64 + m * 16 + l15) * 32 + koff]);
#pragma unroll
        for (int n = 0; n < 4; ++n)
            bf[n] = *reinterpret_cast<const short8*>(&Bs[(wn * 64 + n * 16 + l15) * 32 + koff]);
#pragma unroll
        for (int m = 0; m < 4; ++m)
#pragma unroll
            for (int n = 0; n < 4; ++n)
                acc[m][n] = __builtin_amdgcn_mfma_f32_16x16x32_bf16(af[m], bf[n], acc[m][n], 0, 0, 0);
    }
#pragma unroll
    for (int m = 0; m < 4; ++m)
#pragma unroll
        for (int n = 0; n < 4; ++n)
#pragma unroll
            for (int r = 0; r < 4; ++r) {
                int row = bm * 128 + wm * 64 + m * 16 + ((l >> 4) << 2) + r;
                int col = bn * 128 + wn * 64 + n * 16 + l15;
                float v = acc[m][n][r];
                if (OUT_F32) reinterpret_cast<float*>(Cv)[(size_t)row * N + col] = v;
                else reinterpret_cast<unsigned short*>(Cv)[(size_t)row * N + col] = f2b(v);
            }
    if (DO_KRED) {
        int hw = bn * 2 + wn;  // wave's 64 cols = one head
#pragma unroll
        for (int m = 0; m < 4; ++m) {
            f32x4 rs = (acc[m][0] + acc[m][1]) + (acc[m][2] + acc[m][3]);
#pragma unroll
            for (int d = 1; d < 16; d <<= 1) {
                f32x4 t;
                t[0] = __shfl_xor(rs[0], d); t[1] = __shfl_xor(rs[1], d);
                t[2] = __shfl_xor(rs[2], d); t[3] = __shfl_xor(rs[3], d);
                rs += t;
            }
            if (l15 == 0) {
#pragma unroll
                for (int r = 0; r < 4; ++r) {
                    int row = bm * 128 + wm * 64 + m * 16 + ((l >> 4) << 2) + r;
                    kredT[((size_t)((row >> 10) * 16 + hw) << 10) + (row & 1023)] = rs[r] * 0.125f;
                }
            }
        }
    }
}

__global__ void __launch_bounds__(256) gemm_qkv(const unsigned short* __restrict__ Sb,
                                                const unsigned short* __restrict__ Kb,
                                                const unsigned short* __restrict__ W3,
                                                unsigned short* __restrict__ Qb,
                                                unsigned short* __restrict__ Kbf,
                                                unsigned short* __restrict__ Vb,
                                                float* __restrict__ kredT) {
    __shared__ unsigned short As[128 * 32];
    __shared__ unsigned short Bs[128 * 32];
    int g = blockIdx.x >> 8, sub = blockIdx.x & 255;
    const unsigned short* A = (g == 0) ? Sb : Kb;
    const unsigned short* Bt = W3 + (size_t)g * (1024 * 1024);
    unsigned short* C = (g == 0) ? Qb : ((g == 1) ? Kbf : Vb);
    if (g == 1)
        gemm128_body<0, 1>(A, Bt, C, sub >> 3, sub & 7, As, Bs, kredT);
    else
        gemm128_body<0, 0>(A, Bt, C, sub >> 3, sub & 7, As, Bs, nullptr);
}

__global__ void __launch_bounds__(256) gemm_wo(const unsigned short* __restrict__ A,
                                               const unsigned short* __restrict__ Bt,
                                               float* __restrict__ C) {
    __shared__ unsigned short As[128 * 32];
    __shared__ unsigned short Bs[128 * 32];
    gemm128_body<1, 0>(A, Bt, C, blockIdx.x >> 3, blockIdx.x & 7, As, Bs, nullptr);
}

// ---------------- zero bqkT (blocks 0..4095) + V transpose (4096..5119) ------------------
__global__ void __launch_bounds__(256) zero_tv(float* __restrict__ bqkT,
                                               const unsigned short* __restrict__ V,
                                               unsigned short* __restrict__ Vt) {
    __shared__ unsigned short t[64][66];
    int bid = blockIdx.x, tid = threadIdx.x;
    if (bid < 4096) {
        float4 z = {0.f, 0.f, 0.f, 0.f};
        reinterpret_cast<float4*>(bqkT)[bid * 256 + tid] = z;
        return;
    }
    int vb = bid - 4096;
    int st = vb & 15, h = (vb >> 4) & 15, b = vb >> 8;
    int s = tid >> 2, c16 = (tid & 3) << 4;
    const unsigned short* src = V + ((size_t)((b * 1024 + st * 64 + s) * 16 + h)) * 64 + c16;
    short8 v0 = *reinterpret_cast<const short8*>(src);
    short8 v1 = *reinterpret_cast<const short8*>(src + 8);
    for (int j = 0; j < 8; ++j) {
        t[s][c16 + j] = (unsigned short)v0[j];
        t[s][c16 + 8 + j] = (unsigned short)v1[j];
    }
    __syncthreads();
    int a = tid >> 2, s16 = (tid & 3) << 4;
    short8 o0, o1;
    for (int j = 0; j < 8; ++j) {
        o0[j] = (short)t[s16 + j][a];
        o1[j] = (short)t[s16 + 8 + j][a];
    }
    unsigned short* dst = Vt + ((size_t)((b * 16 + h) * 64 + a)) * 1024 + st * 64 + s16;
    *reinterpret_cast<short8*>(dst) = o0;
    *reinterpret_cast<short8*>(dst + 8) = o1;
}

// ---------------- sparse bias scatter (transposed) with LDS value table ------------------
__global__ void __launch_bounds__(256) scatter_bias(const int* __restrict__ ab,
                                                    const float* __restrict__ embs,
                                                    const float* __restrict__ scal,
                                                    float* __restrict__ bqkT, int n) {
    __shared__ float tab[64];
    int tid = threadIdx.x;
    if (tid < 64) {
        float v = 0.f;
        for (int a = 0; a < 64; ++a) v += embs[tid * 64 + a] * scal[a];
        tab[tid] = v;
    }
    __syncthreads();
    int i = blockIdx.x * 256 + tid;
    if (i >= n) return;
    int4 e = *reinterpret_cast<const int4*>(&ab[i * 4]);  // (b, q, k, eid)
    atomicAdd(&bqkT[((size_t)e.x * 1024 + e.z) * 1024 + e.y], tab[e.w]);
}

// ---------------- pack_T: pkT[b][k][q] = bf16(mask[b,q,k])<<16 | bf16(bqkT[b][k][q]) ------
__global__ void __launch_bounds__(256) pack_T(const float* __restrict__ masks,
                                              unsigned* __restrict__ pkT) {
    __shared__ float mt[64][65];
    int bid = blockIdx.x;
    int qt = bid & 15, ktile = (bid >> 4) & 15, b = bid >> 8;
    int tid = threadIdx.x;
    int row = tid >> 2, c16 = (tid & 3) << 4;
    const float* mrow = masks + ((size_t)(b * 1024 + qt * 64 + row)) * 1024 + ktile * 64 + c16;
    for (int j = 0; j < 16; j += 4) {
        float4 v = *reinterpret_cast<const float4*>(mrow + j);
        mt[row][c16 + j] = v.x; mt[row][c16 + j + 1] = v.y;
        mt[row][c16 + j + 2] = v.z; mt[row][c16 + j + 3] = v.w;
    }
    __syncthreads();
    unsigned* orow = pkT + ((size_t)(b * 1024 + ktile * 64 + row)) * 1024 + qt * 64 + c16;
    for (int j = 0; j < 16; j += 4) {
        float4 bv = *reinterpret_cast<const float4*>(reinterpret_cast<float*>(orow + j));
        uint4v o;
        o.x = ((unsigned)f2b(mt[c16 + j][row]) << 16)     | f2b(bv.x);
        o.y = ((unsigned)f2b(mt[c16 + j + 1][row]) << 16) | f2b(bv.y);
        o.z = ((unsigned)f2b(mt[c16 + j + 2][row]) << 16) | f2b(bv.z);
        o.w = ((unsigned)f2b(mt[c16 + j + 3][row]) << 16) | f2b(bv.w);
        *reinterpret_cast<uint4v*>(orow + j) = o;
    }
}

// ---------------- fused attention v7 ----------------
// grid 1024: g=bid&63 -> (b,h), qb=bid>>6; 4 waves x 16 q-rows, same head.
__global__ void __launch_bounds__(256, 4) attn_kernel(const unsigned short* __restrict__ Q,
                                                      const unsigned short* __restrict__ K,
                                                      const unsigned short* __restrict__ Vt,
                                                      const unsigned* __restrict__ pkT,
                                                      const float* __restrict__ kredT,
                                                      unsigned short* __restrict__ ctx) {
    __shared__ __align__(16) unsigned short Ks[64 * 64];  // linear + XOR swizzle
    __shared__ __align__(16) unsigned short Vs[64 * 64];
    __shared__ __align__(16) unsigned short p_s[4][16][72];

    int bid = blockIdx.x;
    int g = bid & 63, qb = bid >> 6;
    int b = g >> 4, h = g & 15;
    int tid = threadIdx.x, w = tid >> 6, l = tid & 63;
    int qbase = qb * 64 + w * 16;
    int l15 = l & 15, l16 = l >> 4, koff = l16 << 3;

    // staging: 32 rows x 8 slots per pass, 2 passes (rows +32)
    int srow = tid >> 3, sslot = tid & 7;
    int sbyte = srow * 128 + (((sslot ^ (srow & 7)) & 7) << 4);  // (srow+32)&7 == srow&7

    const unsigned short* Kg = K + ((size_t)b << 20) + h * 64 + sslot * 8;                       // + s*1024
    const unsigned short* Vg = Vt + ((size_t)(b * 16 + h) << 16) + (size_t)srow * 1024 + sslot * 8;  // + k
    const unsigned* pkp = pkT + ((size_t)b << 20) + qbase + l15;                                 // + k*1024
    const float* krp = kredT + ((size_t)(b * 16 + h) << 10);                                     // + k

    short8 qf0, qf1;
    {
        const unsigned short* qp = Q + ((size_t)((b * 1024 + qbase + l15) * 16 + h)) * 64 + koff;
        qf0 = *reinterpret_cast<const short8*>(qp);
        qf1 = *reinterpret_cast<const short8*>(qp + 32);
    }

    // prefetch tile 0
    short8 kpre0 = *reinterpret_cast<const short8*>(Kg + (size_t)srow * 1024);
    short8 kpre1 = *reinterpret_cast<const short8*>(Kg + (size_t)(srow + 32) * 1024);
    short8 vpre0 = *reinterpret_cast<const short8*>(Vg);
    short8 vpre1 = *reinterpret_cast<const short8*>(Vg + (size_t)32 * 1024);
    unsigned pkv[16];
#pragma unroll
    for (int n = 0; n < 4; ++n)
#pragma unroll
        for (int r = 0; r < 4; ++r)
            pkv[n * 4 + r] = pkp[(size_t)(n * 16 + l16 * 4 + r) << 10];
    f32x4 kr4[4];
#pragma unroll
    for (int n = 0; n < 4; ++n)
        kr4[n] = *reinterpret_cast<const f32x4*>(&krp[n * 16 + (l16 << 2)]);

    float m_r = -INFINITY, l_r = 0.f;  // per-lane, q = qbase + l15
    f32x4 O[4] = {};

    for (int kt = 0; kt < 16; ++kt) {
        int kbase = kt * 64;

        __syncthreads();  // all waves done reading Ks/Vs of previous tile
        *reinterpret_cast<short8*>(reinterpret_cast<char*>(Ks) + sbyte) = kpre0;
        *reinterpret_cast<short8*>(reinterpret_cast<char*>(Ks) + 32 * 128 + sbyte) = kpre1;
        *reinterpret_cast<short8*>(reinterpret_cast<char*>(Vs) + sbyte) = vpre0;
        *reinterpret_cast<short8*>(reinterpret_cast<char*>(Vs) + 32 * 128 + sbyte) = vpre1;
        __syncthreads();  // staged tile visible

        if (kt < 15) {
            int nb = kbase + 64;
            kpre0 = *reinterpret_cast<const short8*>(Kg + (size_t)(nb + srow) * 1024);
            kpre1 = *reinterpret_cast<const short8*>(Kg + (size_t)(nb + srow + 32) * 1024);
            vpre0 = *reinterpret_cast<const short8*>(Vg + nb);
            vpre1 = *reinterpret_cast<const short8*>(Vg + (size_t)32 * 1024 + nb);
        }

        // QK^T swapped: C[row=k][col=q]; Q pre-scaled by 0.125
        f32x4 sacc[4] = {};
#pragma unroll
        for (int n = 0; n < 4; ++n) {
            int rk = n * 16 + l15;
            short8 kf0 = ldkv(Ks, rk, l16);
            short8 kf1 = ldkv(Ks, rk, 4 + l16);
            sacc[n] = __builtin_amdgcn_mfma_f32_16x16x32_bf16(kf0, qf0, sacc[n], 0, 0, 0);
            sacc[n] = __builtin_amdgcn_mfma_f32_16x16x32_bf16(kf1, qf1, sacc[n], 0, 0, 0);
        }

        // logits in place (kred pre-scaled 0.125, broadcast float4)
        float tmax = -INFINITY;
#pragma unroll
        for (int n = 0; n < 4; ++n)
#pragma unroll
            for (int r = 0; r < 4; ++r) {
                unsigned pv = pkv[n * 4 + r];
                float mv = hi_as_f(pv);
                float bq = lo_as_f(pv);
                float v = fmaf(bq, kr4[n][r], sacc[n][r]) * mv;
                if (!(mv > 0.f)) v += NEG_MIN;
                sacc[n][r] = v;
                tmax = fmaxf(tmax, v);
            }
        tmax = fmaxf(tmax, __shfl_xor(tmax, 16));
        tmax = fmaxf(tmax, __shfl_xor(tmax, 32));

        // defer-max (T13): skip rescale when max growth <= 5 nat-log units
        bool defer = __all(tmax - m_r <= 5.f);
        if (!defer) {
            float nm = fmaxf(m_r, tmax);
            float al = exp2f((m_r - nm) * LOG2E);
            m_r = nm;
            l_r *= al;
            float alr[4];
#pragma unroll
            for (int r = 0; r < 4; ++r) alr[r] = __shfl(al, l16 * 4 + r);
#pragma unroll
            for (int af = 0; af < 4; ++af)
#pragma unroll
                for (int r = 0; r < 4; ++r) O[af][r] *= alr[r];
        }

        float ps = 0.f;
#pragma unroll
        for (int n = 0; n < 4; ++n) {
            float p0 = exp2f((sacc[n][0] - m_r) * LOG2E) * hi_as_f(pkv[n * 4 + 0]);
            float p1 = exp2f((sacc[n][1] - m_r) * LOG2E) * hi_as_f(pkv[n * 4 + 1]);
            float p2 = exp2f((sacc[n][2] - m_r) * LOG2E) * hi_as_f(pkv[n * 4 + 2]);
            float p3 = exp2f((sacc[n][3] - m_r) * LOG2E) * hi_as_f(pkv[n * 4 + 3]);
            ps += (p0 + p1) + (p2 + p3);
            uint2v pk2;
            asm("v_cvt_pk_bf16_f32 %0, %1, %2" : "=v"(pk2.x) : "v"(p0), "v"(p1));
            asm("v_cvt_pk_bf16_f32 %0, %1, %2" : "=v"(pk2.y) : "v"(p2), "v"(p3));
            *reinterpret_cast<uint2v*>(&p_s[w][l15][n * 16 + (l16 << 2)]) = pk2;
        }
        // NOTE: ps sums MASKED p (mask 0/1 exact in bf16; matches ref: masked
        // logits are NEG_MIN -> exp ~ 0 anyway; multiply keeps exact zero).

        if (kt < 15) {
#pragma unroll
            for (int n = 0; n < 4; ++n)
#pragma unroll
                for (int r = 0; r < 4; ++r)
                    pkv[n * 4 + r] = pkp[(size_t)(kbase + 64 + n * 16 + l16 * 4 + r) << 10];
#pragma unroll
            for (int n = 0; n < 4; ++n)
                kr4[n] = *reinterpret_cast<const f32x4*>(&krp[kbase + 64 + n * 16 + (l16 << 2)]);
        }

        ps += __shfl_xor(ps, 16);
        ps += __shfl_xor(ps, 32);
        l_r += ps;

        // PV: A = per-wave P tile (LDS), B = staged V rows (swizzled)
#pragma unroll
        for (int ks = 0; ks < 2; ++ks) {
            short8 pa = *reinterpret_cast<const short8*>(&p_s[w][l15][ks * 32 + koff]);
#pragma unroll
            for (int af = 0; af < 4; ++af) {
                short8 vb = ldkv(Vs, af * 16 + l15, ks * 4 + l16);
                O[af] = __builtin_amdgcn_mfma_f32_16x16x32_bf16(pa, vb, O[af], 0, 0, 0);
            }
        }
    }

    float llr[4];
#pragma unroll
    for (int r = 0; r < 4; ++r) llr[r] = __shfl(l_r, l16 * 4 + r);
#pragma unroll
    for (int af = 0; af < 4; ++af)
#pragma unroll
        for (int r = 0; r < 4; ++r) {
            int row = l16 * 4 + r;
            float v = O[af][r] / llr[r];
            ctx[((size_t)((b * 1024 + qbase + row) * 16 + h)) * 64 + af * 16 + l15] = f2b(v);
        }
}

// ---------------- host launch ----------------
extern "C" void kernel_launch(void* const* d_in, const int* in_sizes, int n_in,
                              void* d_out, int out_size, void* d_ws, size_t ws_size,
                              hipStream_t stream) {
    const float* states     = (const float*)d_in[0];
    const float* key_states = (const float*)d_in[1];
    const float* masks      = (const float*)d_in[2];
    const int*   ab         = (const int*)d_in[3];
    const float* Wq         = (const float*)d_in[4];
    const float* Wk         = (const float*)d_in[5];
    const float* Wv         = (const float*)d_in[6];
    const float* Wo         = (const float*)d_in[7];
    const float* embs       = (const float*)d_in[8];
    const float* scal       = (const float*)d_in[9];

    char* ws = (char*)d_ws;
    const size_t MB = 1024 * 1024;
    unsigned short* Sb   = (unsigned short*)(ws);
    unsigned short* Kb   = (unsigned short*)(ws + 8 * MB);
    float*          bqkT = (float*)(ws);                     // overlays Sb/Kb after QKV GEMM
    unsigned short* Wqt  = (unsigned short*)(ws + 16 * MB);  // Wq^T,Wk^T,Wv^T (6MB)
    unsigned short* Wot  = (unsigned short*)(ws + 22 * MB);
    unsigned short* Qb   = (unsigned short*)(ws + 24 * MB);
    unsigned short* Kbf  = (unsigned short*)(ws + 32 * MB);
    unsigned short* Vb   = (unsigned short*)(ws + 40 * MB);  // dead after zero_tv
    unsigned short* ctx  = (unsigned short*)(ws + 40 * MB);  // reuses Vb region
    unsigned short* Vt   = (unsigned short*)(ws + 48 * MB);
    float*          krdT = (float*)(ws + 56 * MB);           // 256KB
    (void)in_sizes; (void)n_in; (void)out_size; (void)ws_size;

    prep_kernel<<<9216, 256, 0, stream>>>(states, key_states, Wq, Wk, Wv, Wo, Sb, Kb, Wqt, Wot);

    gemm_qkv<<<768, 256, 0, stream>>>(Sb, Kb, Wqt, Qb, Kbf, Vb, krdT);

    // zero bqkT (overlays Sb/Kb; safe after gemm_qkv) + transpose V in one launch
    zero_tv<<<5120, 256, 0, stream>>>(bqkT, Vb, Vt);
    scatter_bias<<<64, 256, 0, stream>>>(ab, embs, scal, bqkT, 16384);
    pack_T<<<1024, 256, 0, stream>>>(masks, (unsigned*)bqkT);

    attn_kernel<<<1024, 256, 0, stream>>>(Qb, Kbf, Vt, (const unsigned*)bqkT, krdT, ctx);

    gemm_wo<<<256, 256, 0, stream>>>(ctx, Wot, (float*)d_out);
}

// Round 8
// 157.020 us; speedup vs baseline: 2.2316x; 1.0172x over previous
//
#include <hip/hip_runtime.h>
#include <stdint.h>

// AttentionLayer_27599459844127 — round 7:
//  * pkT reshaped to [b][kt][q][kk] (4D tile layout): attn gathers 16 dwords ->
//    4 dwordx4 with imm offsets (saves ~44 VALU + 12 VMEM per tile per wave).
//  * attn v8: drop p*mask (masked logits NEG_MIN -> exp == 0 exactly),
//    s_setprio around MFMA clusters.
//  * GEMM BK=64: half the barriers; linear global_load_lds dest + inverse-
//    swizzled global source + swizzled ds_read (m201 both-sides rule).

typedef __attribute__((ext_vector_type(8))) short short8;
typedef __attribute__((ext_vector_type(4))) float f32x4;
typedef __attribute__((ext_vector_type(4))) unsigned short ushort4v;
typedef __attribute__((ext_vector_type(2))) unsigned uint2v;
typedef __attribute__((ext_vector_type(4))) unsigned uint4v;

#define DEVI __device__ __forceinline__

constexpr float NEG_MIN = -3.4028234663852886e38f;
constexpr float LOG2E   = 1.4426950408889634f;

DEVI unsigned short f2b(float f) {
    union { float f; unsigned u; } x; x.f = f;
    unsigned u = x.u;
    unsigned r = (u + 0x7fffu + ((u >> 16) & 1u)) >> 16;  // RNE
    return (unsigned short)r;
}
DEVI float hi_as_f(unsigned p) { union { unsigned u; float f; } x; x.u = p & 0xffff0000u; return x.f; }
DEVI float lo_as_f(unsigned p) { union { unsigned u; float f; } x; x.u = p << 16; return x.f; }
DEVI float asf(unsigned u) { union { unsigned u; float f; } x; x.u = u; return x.f; }

DEVI void gl_lds16(const unsigned short* g, unsigned short* l) {
    __builtin_amdgcn_global_load_lds(
        (const __attribute__((address_space(1))) unsigned int*)g,
        (__attribute__((address_space(3))) unsigned int*)l, 16, 0, 0);
}

// swizzled LDS read for 128B rows: row*128B + (slot^(row&7))*16B
DEVI short8 ldswz(const unsigned short* base, int row, int slot) {
    return *reinterpret_cast<const short8*>(
        reinterpret_cast<const char*>(base) + row * 128 + (((slot ^ row) & 7) << 4));
}

// ---------------- prep: cast inputs (blocks 0..8191) + weight transpose (8192..9215) -----
__global__ void __launch_bounds__(256) prep_kernel(const float* __restrict__ s0,
                                                   const float* __restrict__ s1,
                                                   const float* __restrict__ Wq,
                                                   const float* __restrict__ Wk,
                                                   const float* __restrict__ Wv,
                                                   const float* __restrict__ Wo,
                                                   unsigned short* __restrict__ d0,
                                                   unsigned short* __restrict__ d1,
                                                   unsigned short* __restrict__ Wqt,
                                                   unsigned short* __restrict__ Wot) {
    __shared__ float t[64][65];
    int bid = blockIdx.x, tid = threadIdx.x;
    if (bid < 8192) {
        int i = bid * 256 + tid;
        const float* src = (i < 1024 * 1024) ? s0 : s1;
        unsigned short* dst = (i < 1024 * 1024) ? d0 : d1;
        int j = i & (1024 * 1024 - 1);
        float4 v = reinterpret_cast<const float4*>(src)[j];
        ushort4v o;
        o.x = f2b(v.x); o.y = f2b(v.y); o.z = f2b(v.z); o.w = f2b(v.w);
        reinterpret_cast<ushort4v*>(dst)[j] = o;
        return;
    }
    int wb = bid - 8192;
    int wi = wb >> 8, sub = wb & 255;
    const float* src = (wi == 0) ? Wq : ((wi == 1) ? Wk : ((wi == 2) ? Wv : Wo));
    unsigned short* dst = (wi == 3) ? Wot : (Wqt + (size_t)wi * 1024 * 1024);
    float scale = (wi == 0) ? 0.125f : 1.0f;
    const int R = 1024, C = 1024;
    int bc = sub & 15, br = sub >> 4;
    int r0 = tid >> 4, c4 = (tid & 15) << 2;
    for (int i = 0; i < 4; ++i) {
        int row = r0 + i * 16;
        float4 v = *reinterpret_cast<const float4*>(&src[(size_t)(br * 64 + row) * C + bc * 64 + c4]);
        t[row][c4] = v.x; t[row][c4 + 1] = v.y; t[row][c4 + 2] = v.z; t[row][c4 + 3] = v.w;
    }
    __syncthreads();
    int cr0 = tid >> 4, r4 = (tid & 15) << 2;
    for (int i = 0; i < 4; ++i) {
        int crow = cr0 + i * 16;
        ushort4v o;
        o.x = f2b(t[r4][crow] * scale); o.y = f2b(t[r4 + 1][crow] * scale);
        o.z = f2b(t[r4 + 2][crow] * scale); o.w = f2b(t[r4 + 3][crow] * scale);
        *reinterpret_cast<ushort4v*>(&dst[(size_t)(bc * 64 + crow) * R + br * 64 + r4]) = o;
    }
}

// ---------------- GEMM 128x128 tile, BK=64, swizzled gl_lds staging ----------------------
template <int OUT_F32, int DO_KRED>
DEVI void gemm128_body(const unsigned short* __restrict__ A,
                       const unsigned short* __restrict__ Bt,
                       void* __restrict__ Cv, int bm, int bn,
                       unsigned short* As, unsigned short* Bs,
                       float* __restrict__ kredT) {
    const int Kd = 1024, N = 1024;
    int tid = threadIdx.x, l = tid & 63, w = tid >> 6;
    int wm = w >> 1, wn = w & 1;
    int l15 = l & 15, l16 = l >> 4;
    f32x4 acc[4][4] = {};
    // staging: lane l -> row chunk lr = l>>3 (8 rows/wave/instr), slot ls = l&7.
    // LDS dest is linear; global source col is inverse-swizzled so LDS[row][j]
    // holds global chunk j^(row&7).
    int lr = l >> 3, ls = l & 7;
    int gcol = ((ls ^ (lr & 7)) << 3);  // shorts
    const unsigned short* Ag = A + (size_t)(bm * 128 + w * 8 + lr) * Kd + gcol;
    const unsigned short* Bg = Bt + (size_t)(bn * 128 + w * 8 + lr) * Kd + gcol;
    unsigned short* AsW = As + (w * 8) * 64;
    unsigned short* BsW = Bs + (w * 8) * 64;
    for (int kt = 0; kt < Kd; kt += 64) {
        __syncthreads();  // previous tile consumed
#pragma unroll
        for (int i = 0; i < 4; ++i) {
            gl_lds16(Ag + kt + (size_t)(i * 32) * Kd, AsW + i * 32 * 64);
            gl_lds16(Bg + kt + (size_t)(i * 32) * Kd, BsW + i * 32 * 64);
        }
        __syncthreads();  // vmcnt drained -> tile visible
#pragma unroll
        for (int h = 0; h < 2; ++h) {
            short8 af[4], bf[4];
#pragma unroll
            for (int m = 0; m < 4; ++m)
                af[m] = ldswz(As, wm * 64 + m * 16 + l15, h * 4 + l16);
#pragma unroll
            for (int n = 0; n < 4; ++n)
                bf[n] = ldswz(Bs, wn * 64 + n * 16 + l15, h * 4 + l16);
#pragma unroll
            for (int m = 0; m < 4; ++m)
#pragma unroll
                for (int n = 0; n < 4; ++n)
                    acc[m][n] = __builtin_amdgcn_mfma_f32_16x16x32_bf16(af[m], bf[n], acc[m][n], 0, 0, 0);
        }
    }
#pragma unroll
    for (int m = 0; m < 4; ++m)
#pragma unroll
        for (int n = 0; n < 4; ++n)
#pragma unroll
            for (int r = 0; r < 4; ++r) {
                int row = bm * 128 + wm * 64 + m * 16 + ((l >> 4) << 2) + r;
                int col = bn * 128 + wn * 64 + n * 16 + l15;
                float v = acc[m][n][r];
                if (OUT_F32) reinterpret_cast<float*>(Cv)[(size_t)row * N + col] = v;
                else reinterpret_cast<unsigned short*>(Cv)[(size_t)row * N + col] = f2b(v);
            }
    if (DO_KRED) {
        int hw = bn * 2 + wn;  // wave's 64 cols = one head
#pragma unroll
        for (int m = 0; m < 4; ++m) {
            f32x4 rs = (acc[m][0] + acc[m][1]) + (acc[m][2] + acc[m][3]);
#pragma unroll
            for (int d = 1; d < 16; d <<= 1) {
                f32x4 t;
                t[0] = __shfl_xor(rs[0], d); t[1] = __shfl_xor(rs[1], d);
                t[2] = __shfl_xor(rs[2], d); t[3] = __shfl_xor(rs[3], d);
                rs += t;
            }
            if (l15 == 0) {
#pragma unroll
                for (int r = 0; r < 4; ++r) {
                    int row = bm * 128 + wm * 64 + m * 16 + ((l >> 4) << 2) + r;
                    kredT[((size_t)((row >> 10) * 16 + hw) << 10) + (row & 1023)] = rs[r] * 0.125f;
                }
            }
        }
    }
}

__global__ void __launch_bounds__(256) gemm_qkv(const unsigned short* __restrict__ Sb,
                                                const unsigned short* __restrict__ Kb,
                                                const unsigned short* __restrict__ W3,
                                                unsigned short* __restrict__ Qb,
                                                unsigned short* __restrict__ Kbf,
                                                unsigned short* __restrict__ Vb,
                                                float* __restrict__ kredT) {
    __shared__ unsigned short As[128 * 64];
    __shared__ unsigned short Bs[128 * 64];
    int g = blockIdx.x >> 8, sub = blockIdx.x & 255;
    const unsigned short* A = (g == 0) ? Sb : Kb;
    const unsigned short* Bt = W3 + (size_t)g * (1024 * 1024);
    unsigned short* C = (g == 0) ? Qb : ((g == 1) ? Kbf : Vb);
    if (g == 1)
        gemm128_body<0, 1>(A, Bt, C, sub >> 3, sub & 7, As, Bs, kredT);
    else
        gemm128_body<0, 0>(A, Bt, C, sub >> 3, sub & 7, As, Bs, nullptr);
}

__global__ void __launch_bounds__(256) gemm_wo(const unsigned short* __restrict__ A,
                                               const unsigned short* __restrict__ Bt,
                                               float* __restrict__ C) {
    __shared__ unsigned short As[128 * 64];
    __shared__ unsigned short Bs[128 * 64];
    gemm128_body<1, 0>(A, Bt, C, blockIdx.x >> 3, blockIdx.x & 7, As, Bs, nullptr);
}

// ---------------- zero pkT2 (blocks 0..4095) + V transpose (4096..5119) ------------------
__global__ void __launch_bounds__(256) zero_tv(float* __restrict__ bqkT,
                                               const unsigned short* __restrict__ V,
                                               unsigned short* __restrict__ Vt) {
    __shared__ unsigned short t[64][66];
    int bid = blockIdx.x, tid = threadIdx.x;
    if (bid < 4096) {
        float4 z = {0.f, 0.f, 0.f, 0.f};
        reinterpret_cast<float4*>(bqkT)[bid * 256 + tid] = z;
        return;
    }
    int vb = bid - 4096;
    int st = vb & 15, h = (vb >> 4) & 15, b = vb >> 8;
    int s = tid >> 2, c16 = (tid & 3) << 4;
    const unsigned short* src = V + ((size_t)((b * 1024 + st * 64 + s) * 16 + h)) * 64 + c16;
    short8 v0 = *reinterpret_cast<const short8*>(src);
    short8 v1 = *reinterpret_cast<const short8*>(src + 8);
    for (int j = 0; j < 8; ++j) {
        t[s][c16 + j] = (unsigned short)v0[j];
        t[s][c16 + 8 + j] = (unsigned short)v1[j];
    }
    __syncthreads();
    int a = tid >> 2, s16 = (tid & 3) << 4;
    short8 o0, o1;
    for (int j = 0; j < 8; ++j) {
        o0[j] = (short)t[s16 + j][a];
        o1[j] = (short)t[s16 + 8 + j][a];
    }
    unsigned short* dst = Vt + ((size_t)((b * 16 + h) * 64 + a)) * 1024 + st * 64 + s16;
    *reinterpret_cast<short8*>(dst) = o0;
    *reinterpret_cast<short8*>(dst + 8) = o1;
}

// ---------------- sparse bias scatter into 4D layout [b][kt][q][kk] ----------------------
__global__ void __launch_bounds__(256) scatter_bias(const int* __restrict__ ab,
                                                    const float* __restrict__ embs,
                                                    const float* __restrict__ scal,
                                                    float* __restrict__ pk2f, int n) {
    __shared__ float tab[64];
    int tid = threadIdx.x;
    if (tid < 64) {
        float v = 0.f;
        for (int a = 0; a < 64; ++a) v += embs[tid * 64 + a] * scal[a];
        tab[tid] = v;
    }
    __syncthreads();
    int i = blockIdx.x * 256 + tid;
    if (i >= n) return;
    int4 e = *reinterpret_cast<const int4*>(&ab[i * 4]);  // (b, q, k, eid)
    size_t idx = (((size_t)(e.x * 16 + (e.z >> 6)) * 1024) + e.y) * 64 + (e.z & 63);
    atomicAdd(&pk2f[idx], tab[e.w]);
}

// ---------------- pack: pk2[b][kt][q][kk] = bf16(mask[b,q,kt*64+kk])<<16 | bf16(bias) ----
__global__ void __launch_bounds__(256) pack_T(const float* __restrict__ masks,
                                              unsigned* __restrict__ pk2) {
    __shared__ float mt[64][65];
    int bid = blockIdx.x;
    int qb = bid & 15, kt = (bid >> 4) & 15, b = bid >> 8;
    int tid = threadIdx.x;
    int ql = tid >> 2, c = tid & 3;
    const float* mrow = masks + ((size_t)(b * 1024 + qb * 64 + ql)) * 1024 + kt * 64 + c * 16;
#pragma unroll
    for (int j = 0; j < 4; ++j) {
        float4 v = *reinterpret_cast<const float4*>(mrow + j * 4);
        mt[ql][c * 16 + j * 4 + 0] = v.x; mt[ql][c * 16 + j * 4 + 1] = v.y;
        mt[ql][c * 16 + j * 4 + 2] = v.z; mt[ql][c * 16 + j * 4 + 3] = v.w;
    }
    __syncthreads();
    unsigned* orow = pk2 + (((size_t)(b * 16 + kt) * 1024) + qb * 64 + ql) * 64 + c * 16;
#pragma unroll
    for (int j = 0; j < 4; ++j) {
        uint4v bv = *reinterpret_cast<const uint4v*>(orow + j * 4);  // f32 bias bits
        uint4v o;
        o.x = ((unsigned)f2b(mt[ql][c * 16 + j * 4 + 0]) << 16) | f2b(asf(bv.x));
        o.y = ((unsigned)f2b(mt[ql][c * 16 + j * 4 + 1]) << 16) | f2b(asf(bv.y));
        o.z = ((unsigned)f2b(mt[ql][c * 16 + j * 4 + 2]) << 16) | f2b(asf(bv.z));
        o.w = ((unsigned)f2b(mt[ql][c * 16 + j * 4 + 3]) << 16) | f2b(asf(bv.w));
        *reinterpret_cast<uint4v*>(orow + j * 4) = o;
    }
}

// ---------------- fused attention v8 ----------------
// grid 1024: g=bid&63 -> (b,h), qb=bid>>6; 4 waves x 16 q-rows, same head.
__global__ void __launch_bounds__(256, 4) attn_kernel(const unsigned short* __restrict__ Q,
                                                      const unsigned short* __restrict__ K,
                                                      const unsigned short* __restrict__ Vt,
                                                      const unsigned* __restrict__ pk2,
                                                      const float* __restrict__ kredT,
                                                      unsigned short* __restrict__ ctx) {
    __shared__ __align__(16) unsigned short Ks[64 * 64];  // linear + XOR swizzle
    __shared__ __align__(16) unsigned short Vs[64 * 64];
    __shared__ __align__(16) unsigned short p_s[4][16][72];

    int bid = blockIdx.x;
    int g = bid & 63, qb = bid >> 6;
    int b = g >> 4, h = g & 15;
    int tid = threadIdx.x, w = tid >> 6, l = tid & 63;
    int qbase = qb * 64 + w * 16;
    int l15 = l & 15, l16 = l >> 4, koff = l16 << 3;

    int srow = tid >> 3, sslot = tid & 7;
    int sbyte = srow * 128 + (((sslot ^ srow) & 7) << 4);

    const unsigned short* Kg = K + ((size_t)b << 20) + h * 64 + sslot * 8;
    const unsigned short* Vg = Vt + ((size_t)(b * 16 + h) << 16) + (size_t)srow * 1024 + sslot * 8;
    // pk2 4D layout: dword idx = ((b*16+kt)*1024 + q)*64 + kk; per-lane base at q=qbase+l15, kk=l16*4
    const unsigned* pkp = pk2 + ((size_t)b << 20) + (size_t)(qbase + l15) * 64 + (l16 << 2);
    const float* krp = kredT + ((size_t)(b * 16 + h) << 10);

    short8 qf0, qf1;
    {
        const unsigned short* qp = Q + ((size_t)((b * 1024 + qbase + l15) * 16 + h)) * 64 + koff;
        qf0 = *reinterpret_cast<const short8*>(qp);
        qf1 = *reinterpret_cast<const short8*>(qp + 32);
    }

    // prefetch tile 0
    short8 kpre0 = *reinterpret_cast<const short8*>(Kg + (size_t)srow * 1024);
    short8 kpre1 = *reinterpret_cast<const short8*>(Kg + (size_t)(srow + 32) * 1024);
    short8 vpre0 = *reinterpret_cast<const short8*>(Vg);
    short8 vpre1 = *reinterpret_cast<const short8*>(Vg + (size_t)32 * 1024);
    uint4v pku[4];
#pragma unroll
    for (int n = 0; n < 4; ++n) pku[n] = *reinterpret_cast<const uint4v*>(pkp + n * 16);
    f32x4 kr4[4];
#pragma unroll
    for (int n = 0; n < 4; ++n)
        kr4[n] = *reinterpret_cast<const f32x4*>(&krp[n * 16 + (l16 << 2)]);

    float m_r = -INFINITY, l_r = 0.f;  // per-lane, q = qbase + l15
    f32x4 O[4] = {};

    for (int kt = 0; kt < 16; ++kt) {
        int kbase = kt * 64;

        __syncthreads();  // all waves done reading Ks/Vs of previous tile
        *reinterpret_cast<short8*>(reinterpret_cast<char*>(Ks) + sbyte) = kpre0;
        *reinterpret_cast<short8*>(reinterpret_cast<char*>(Ks) + 32 * 128 + sbyte) = kpre1;
        *reinterpret_cast<short8*>(reinterpret_cast<char*>(Vs) + sbyte) = vpre0;
        *reinterpret_cast<short8*>(reinterpret_cast<char*>(Vs) + 32 * 128 + sbyte) = vpre1;
        __syncthreads();  // staged tile visible

        if (kt < 15) {
            int nb = kbase + 64;
            kpre0 = *reinterpret_cast<const short8*>(Kg + (size_t)(nb + srow) * 1024);
            kpre1 = *reinterpret_cast<const short8*>(Kg + (size_t)(nb + srow + 32) * 1024);
            vpre0 = *reinterpret_cast<const short8*>(Vg + nb);
            vpre1 = *reinterpret_cast<const short8*>(Vg + (size_t)32 * 1024 + nb);
        }

        // QK^T swapped: C[row=k][col=q]; Q pre-scaled by 0.125
        f32x4 sacc[4] = {};
        __builtin_amdgcn_s_setprio(1);
#pragma unroll
        for (int n = 0; n < 4; ++n) {
            int rk = n * 16 + l15;
            short8 kf0 = ldswz(Ks, rk, l16);
            short8 kf1 = ldswz(Ks, rk, 4 + l16);
            sacc[n] = __builtin_amdgcn_mfma_f32_16x16x32_bf16(kf0, qf0, sacc[n], 0, 0, 0);
            sacc[n] = __builtin_amdgcn_mfma_f32_16x16x32_bf16(kf1, qf1, sacc[n], 0, 0, 0);
        }
        __builtin_amdgcn_s_setprio(0);

        // logits in place (kred pre-scaled 0.125)
        float tmax = -INFINITY;
#pragma unroll
        for (int n = 0; n < 4; ++n)
#pragma unroll
            for (int r = 0; r < 4; ++r) {
                unsigned pv = pku[n][r];
                float mv = hi_as_f(pv);
                float bq = lo_as_f(pv);
                float v = fmaf(bq, kr4[n][r], sacc[n][r]) * mv;
                if (!(mv > 0.f)) v += NEG_MIN;
                sacc[n][r] = v;
                tmax = fmaxf(tmax, v);
            }
        // pku/kr4 consumed -> rotate next tile's gathers (in flight across softmax+PV)
        if (kt < 15) {
            const unsigned* pn = pkp + (size_t)(kt + 1) * 65536;
#pragma unroll
            for (int n = 0; n < 4; ++n) pku[n] = *reinterpret_cast<const uint4v*>(pn + n * 16);
#pragma unroll
            for (int n = 0; n < 4; ++n)
                kr4[n] = *reinterpret_cast<const f32x4*>(&krp[kbase + 64 + n * 16 + (l16 << 2)]);
        }

        tmax = fmaxf(tmax, __shfl_xor(tmax, 16));
        tmax = fmaxf(tmax, __shfl_xor(tmax, 32));

        // defer-max (T13)
        bool defer = __all(tmax - m_r <= 5.f);
        if (!defer) {
            float nm = fmaxf(m_r, tmax);
            float al = exp2f((m_r - nm) * LOG2E);
            m_r = nm;
            l_r *= al;
            float alr[4];
#pragma unroll
            for (int r = 0; r < 4; ++r) alr[r] = __shfl(al, l16 * 4 + r);
#pragma unroll
            for (int af = 0; af < 4; ++af)
#pragma unroll
                for (int r = 0; r < 4; ++r) O[af][r] *= alr[r];
        }

        float ps = 0.f;
#pragma unroll
        for (int n = 0; n < 4; ++n) {
            // masked elements have logit NEG_MIN -> exp2 underflows to exactly 0
            float p0 = exp2f((sacc[n][0] - m_r) * LOG2E);
            float p1 = exp2f((sacc[n][1] - m_r) * LOG2E);
            float p2 = exp2f((sacc[n][2] - m_r) * LOG2E);
            float p3 = exp2f((sacc[n][3] - m_r) * LOG2E);
            ps += (p0 + p1) + (p2 + p3);
            uint2v pk2v;
            asm("v_cvt_pk_bf16_f32 %0, %1, %2" : "=v"(pk2v.x) : "v"(p0), "v"(p1));
            asm("v_cvt_pk_bf16_f32 %0, %1, %2" : "=v"(pk2v.y) : "v"(p2), "v"(p3));
            *reinterpret_cast<uint2v*>(&p_s[w][l15][n * 16 + (l16 << 2)]) = pk2v;
        }

        ps += __shfl_xor(ps, 16);
        ps += __shfl_xor(ps, 32);
        l_r += ps;

        // PV: A = per-wave P tile (LDS), B = staged V rows (swizzled)
        __builtin_amdgcn_s_setprio(1);
#pragma unroll
        for (int ks = 0; ks < 2; ++ks) {
            short8 pa = *reinterpret_cast<const short8*>(&p_s[w][l15][ks * 32 + koff]);
#pragma unroll
            for (int af = 0; af < 4; ++af) {
                short8 vb = ldswz(Vs, af * 16 + l15, ks * 4 + l16);
                O[af] = __builtin_amdgcn_mfma_f32_16x16x32_bf16(pa, vb, O[af], 0, 0, 0);
            }
        }
        __builtin_amdgcn_s_setprio(0);
    }

    float llr[4];
#pragma unroll
    for (int r = 0; r < 4; ++r) llr[r] = __shfl(l_r, l16 * 4 + r);
#pragma unroll
    for (int af = 0; af < 4; ++af)
#pragma unroll
        for (int r = 0; r < 4; ++r) {
            int row = l16 * 4 + r;
            float v = O[af][r] / llr[r];
            ctx[((size_t)((b * 1024 + qbase + row) * 16 + h)) * 64 + af * 16 + l15] = f2b(v);
        }
}

// ---------------- host launch ----------------
extern "C" void kernel_launch(void* const* d_in, const int* in_sizes, int n_in,
                              void* d_out, int out_size, void* d_ws, size_t ws_size,
                              hipStream_t stream) {
    const float* states     = (const float*)d_in[0];
    const float* key_states = (const float*)d_in[1];
    const float* masks      = (const float*)d_in[2];
    const int*   ab         = (const int*)d_in[3];
    const float* Wq         = (const float*)d_in[4];
    const float* Wk         = (const float*)d_in[5];
    const float* Wv         = (const float*)d_in[6];
    const float* Wo         = (const float*)d_in[7];
    const float* embs       = (const float*)d_in[8];
    const float* scal       = (const float*)d_in[9];

    char* ws = (char*)d_ws;
    const size_t MB = 1024 * 1024;
    unsigned short* Sb   = (unsigned short*)(ws);
    unsigned short* Kb   = (unsigned short*)(ws + 8 * MB);
    float*          pk2f = (float*)(ws);                     // overlays Sb/Kb after QKV GEMM
    unsigned short* Wqt  = (unsigned short*)(ws + 16 * MB);  // Wq^T,Wk^T,Wv^T (6MB)
    unsigned short* Wot  = (unsigned short*)(ws + 22 * MB);
    unsigned short* Qb   = (unsigned short*)(ws + 24 * MB);
    unsigned short* Kbf  = (unsigned short*)(ws + 32 * MB);
    unsigned short* Vb   = (unsigned short*)(ws + 40 * MB);  // dead after zero_tv
    unsigned short* ctx  = (unsigned short*)(ws + 40 * MB);  // reuses Vb region
    unsigned short* Vt   = (unsigned short*)(ws + 48 * MB);
    float*          krdT = (float*)(ws + 56 * MB);           // 256KB
    (void)in_sizes; (void)n_in; (void)out_size; (void)ws_size;

    prep_kernel<<<9216, 256, 0, stream>>>(states, key_states, Wq, Wk, Wv, Wo, Sb, Kb, Wqt, Wot);

    gemm_qkv<<<768, 256, 0, stream>>>(Sb, Kb, Wqt, Qb, Kbf, Vb, krdT);

    // zero pk2 (overlays Sb/Kb; safe after gemm_qkv) + transpose V in one launch
    zero_tv<<<5120, 256, 0, stream>>>(pk2f, Vb, Vt);
    scatter_bias<<<64, 256, 0, stream>>>(ab, embs, scal, pk2f, 16384);
    pack_T<<<1024, 256, 0, stream>>>(masks, (unsigned*)pk2f);

    attn_kernel<<<1024, 256, 0, stream>>>(Qb, Kbf, Vt, (const unsigned*)pk2f, krdT, ctx);

    gemm_wo<<<256, 256, 0, stream>>>(ctx, Wot, (float*)d_out);
}